// Round 15
// baseline (401.406 us; speedup 1.0000x reference)
//
#include <hip/hip_runtime.h>
#include <hip/hip_bf16.h>
#include <math.h>

// Problem constants
#define Bn 2
#define Tn 2048
#define En 1024
#define Hn 16
#define DFFn 4096
#define Mn (Bn*Tn)   // 4096 rows
#define QKVLD 3072   // fused QKV leading dim

typedef __hip_bfloat16 bf16;
typedef unsigned short u16;
typedef unsigned int u32;
typedef __attribute__((ext_vector_type(8))) short short8;
typedef __attribute__((ext_vector_type(4))) float f32x4;

typedef __attribute__((address_space(1))) const void cg_void;
typedef __attribute__((address_space(3))) void lds_void;

// Q pre-scale folded into QKV GEMM: E^-0.5 * log2(e)
#define QSC 0.0450842200278f

// lgkm-only barrier: LDS writes visible + wave sync; vmcnt (global loads in
// flight to wave-private registers) NOT drained -- prefetches survive it.
#define HBAR() asm volatile("s_waitcnt lgkmcnt(0)\n\ts_barrier" ::: "memory")

__device__ __forceinline__ u16 f2bf(float f) {
    bf16 h = __float2bfloat16(f);
    u16 u; __builtin_memcpy(&u, &h, 2); return u;
}
__device__ __forceinline__ float bf2f(u16 u) {
    u32 x = ((u32)u) << 16; float f; __builtin_memcpy(&f, &x, 4); return f;
}

// ---------------- 4x weight transpose+convert (1024x1024 each) ---------------
__global__ __launch_bounds__(256)
void transpose_w4(const float* __restrict__ s0, const float* __restrict__ s1,
                  const float* __restrict__ s2, const float* __restrict__ s3,
                  u16* __restrict__ d0, u16* __restrict__ d1,
                  u16* __restrict__ d2, u16* __restrict__ d3) {
    const float* src = (blockIdx.z == 0) ? s0 : (blockIdx.z == 1) ? s1
                     : (blockIdx.z == 2) ? s2 : s3;
    u16* dst = (blockIdx.z == 0) ? d0 : (blockIdx.z == 1) ? d1
             : (blockIdx.z == 2) ? d2 : d3;
    __shared__ float t[64][65];
    const int r0 = blockIdx.y * 64, c0 = blockIdx.x * 64;
    const int tr = threadIdx.x >> 6, tc = threadIdx.x & 63;
#pragma unroll
    for (int i = 0; i < 16; i++)
        t[tr + i * 4][tc] = src[(size_t)(r0 + tr + i * 4) * 1024 + c0 + tc];
    __syncthreads();
#pragma unroll
    for (int i = 0; i < 16; i++)
        dst[(size_t)(c0 + tr + i * 4) * 1024 + r0 + tc] = f2bf(t[tc][tr + i * 4]);
}

// ---------------- generic weight transpose: src fp32 [R][C] -> bf16 [C][R] ---
__global__ __launch_bounds__(256)
void transpose_w(const float* __restrict__ src, u16* __restrict__ dst,
                 int R, int C) {
    __shared__ float t[64][65];
    const int r0 = blockIdx.y * 64, c0 = blockIdx.x * 64;
    const int tr = threadIdx.x >> 6, tc = threadIdx.x & 63;
#pragma unroll
    for (int i = 0; i < 16; i++)
        t[tr + i * 4][tc] = src[(size_t)(r0 + tr + i * 4) * C + c0 + tc];
    __syncthreads();
#pragma unroll
    for (int i = 0; i < 16; i++)
        dst[(size_t)(c0 + tr + i * 4) * R + r0 + tc] = f2bf(t[tc][tr + i * 4]);
}

// ---------------- V copy-transpose: QKV V-cols -> Vg[bh][dh=64][tok=2048] ----
__global__ __launch_bounds__(256)
void vcopy_t(const u16* __restrict__ QKV, u16* __restrict__ Vg) {
    const int bh = blockIdx.z;          // bb*16+hh
    const int t0 = blockIdx.y * 64;     // token tile
    __shared__ u16 t[64][65];
    const int tr = threadIdx.x >> 6, tc = threadIdx.x & 63;
    const u16* src = QKV + (size_t)(bh >> 4) * 2048 * QKVLD + 2048 + (bh & 15) * 64;
#pragma unroll
    for (int i = 0; i < 16; i++)
        t[tr + i * 4][tc] = src[(size_t)(t0 + tr + i * 4) * QKVLD + tc];  // [tokl][dh]
    __syncthreads();
    u16* dst = Vg + (size_t)bh * 64 * 2048;
#pragma unroll
    for (int i = 0; i < 16; i++)
        dst[(size_t)(tr + i * 4) * 2048 + t0 + tc] = t[tc][tr + i * 4];
}

// ---------------- LayerNorm: one block per row of E=1024 ---------------------
template<typename AT>
__global__ __launch_bounds__(256)
void ln_kernel(const AT* __restrict__ x, const float* __restrict__ g,
               const float* __restrict__ b, u16* __restrict__ out) {
    const int row = blockIdx.x;
    const int tid = threadIdx.x;
    const AT* xp = x + (size_t)row * En;
    float v[4];
    float s = 0.f, sq = 0.f;
#pragma unroll
    for (int i = 0; i < 4; i++) {
        if constexpr (sizeof(AT) == 2) v[i] = bf2f(xp[tid + i * 256]);
        else                           v[i] = (float)xp[tid + i * 256];
        s += v[i];
        sq += v[i] * v[i];
    }
    __shared__ float rs[256], rq[256];
    rs[tid] = s; rq[tid] = sq;
    __syncthreads();
    for (int st = 128; st > 0; st >>= 1) {
        if (tid < st) { rs[tid] += rs[tid + st]; rq[tid] += rq[tid + st]; }
        __syncthreads();
    }
    const float mu  = rs[0] * (1.0f / En);
    const float var = rq[0] * (1.0f / En) - mu * mu;
    const float inv = rsqrtf(var + 1e-5f);
#pragma unroll
    for (int i = 0; i < 4; i++) {
        const int c = tid + i * 256;
        out[(size_t)row * En + c] = f2bf((v[i] - mu) * inv * g[c] + b[c]);
    }
}

// ---------------- FF2 output init: out = X1(bf16) + b2 (fp32) ----------------
__global__ __launch_bounds__(256)
void ff2_init(const u16* __restrict__ X1, const float* __restrict__ b2,
              float* __restrict__ out) {
    const int row = blockIdx.x;
    const int c = threadIdx.x * 4;
    ushort4 a = *(const ushort4*)&X1[(size_t)row * En + c];
    float4 bb = *(const float4*)&b2[c];
    float4 o;
    o.x = bf2f(a.x) + bb.x;
    o.y = bf2f(a.y) + bb.y;
    o.z = bf2f(a.z) + bb.z;
    o.w = bf2f(a.w) + bb.w;
    *(float4*)&out[(size_t)row * En + c] = o;
}

// ---------------- 256xTN ring-4 counted-vmcnt GEMM ---------------------------
// C[M,N] = A(bf16 [M][K]) @ Wt(bf16 [N][K])^T. 256(M) x TN(N) tile, 512 thr
// (8 waves; TN=256: 2Mx4N, per-wave 128x64; TN=128: 4Mx2N, per-wave 64x64).
// R14 counters: 2-phase vmcnt(0) drain = ~94% of each K-step (MfmaUtil 18.7%,
// 15% HBM). Fix (T3+T4+T5): BK=32 HALF-tiles in a ring of 4 LDS buffers
// (same total LDS: 128/96 KB). Stage half t+3 while computing half t;
// vmcnt(3*LD) proves half t landed (in-order retirement); lgkmcnt(0) before
// the release barrier (R7's verified WAR discipline); setprio(1) around the
// MFMA cluster (waves now have stage/compute role diversity).
// Swizzle (both-sides involution): LDS slot (row,cg) holds global colgroup
// cg^(row&3); stage side via per-lane global addr (gload_lds dst is linear:
// lane l -> row lr4=l>>2, cg=l&3), read side applies the same XOR.
// XSWZ: panel-per-XCD remap (R14: FF2 FETCH 135->49 MB). panel by -> XCD
// by&7 at all sites (GY=16); FF2 z-pair shares XCD.
// ATOM: split-K over gridDim.z, fp32 atomicAdd into pre-init'd outF.
// SPLITA: slice z reads A (z==0) or A2 (z==1), local cols [0,Kd).
template<int TN, int HAS_BIAS, int RELU, int SPLITC, int SCQ, int ATOM,
         int SPLITA, int XSWZ>
__global__ __launch_bounds__(512, 2)
void gemm256(const u16* __restrict__ A, const u16* __restrict__ A2, int ldA,
             const u16* __restrict__ Wt, int ldW,
             const float* __restrict__ bias,
             u16* __restrict__ Cout, u16* __restrict__ Cout2,
             float* __restrict__ outF, int ldC, int Kd) {
    constexpr int WGN = (TN == 256) ? 4 : 2;       // waves along N
    constexpr int MF  = (256 / (8 / WGN)) / 16;    // m-frags/wave: 8 or 4
    constexpr int NF  = (TN / WGN) / 16;           // n-frags/wave: 4
    constexpr int LD  = 2 + TN / 128;              // gload_lds per wave/half
    __shared__ __align__(16) u16 As[4][256 * 32];
    __shared__ __align__(16) u16 Bs[4][TN * 32];
    const int tid  = threadIdx.x;
    const int lane = tid & 63, wv = tid >> 6;      // 8 waves
    const int quad = lane >> 4, l16 = lane & 15;
    const int wr = wv / WGN, wc = wv % WGN;
    const int lr4 = lane >> 2;                     // row within 16-row group
    const int gcg = (lane & 3) ^ (lr4 & 3);        // swizzled source colgroup

    int bx = blockIdx.x, by = blockIdx.y, bz = blockIdx.z;
    if (XSWZ) {
        const int GX = gridDim.x, GY = gridDim.y;  // GY == 16 at all sites
        const int L = (bz * GY + by) * GX + bx;    // hw dispatch order
        const int xcd = L & 7, slot = L >> 3;
        const int p = slot / GX;                   // panel index on this XCD
        bx = slot - p * GX;                        // x sweeps consecutively
        const int yz = p * 8 + xcd;                // (y,z) panel, XCD-resident
        by = yz & (GY - 1);
        bz = yz >> 4;                              // GY=16
    }

    const int m0 = by * 256, n0 = bx * TN;
    const u16* Ap = (SPLITA && ATOM && bz) ? A2 : A;
    const int kbase = ATOM ? bz * Kd : 0;          // B-side global K offset

    f32x4 acc[MF][NF] = {};

    // stage one BK=32 half-tile: per wave-load 64 lanes x 16B = 16 rows x 32
    auto stage = [&](int buf, int kt) {            // kt = local A col (32-mult)
#pragma unroll
        for (int i = 0; i < 2; i++) {              // A: 256 rows = 2 x 128
            const int rbase = i * 128 + wv * 16;
            __builtin_amdgcn_global_load_lds(
                (cg_void*)(const void*)&Ap[(size_t)(m0 + rbase + lr4) * ldA + kt + gcg * 8],
                (lds_void*)(void*)&As[buf][rbase * 32], 16, 0, 0);
        }
#pragma unroll
        for (int i = 0; i < TN / 128; i++) {       // B: TN rows
            const int rbase = i * 128 + wv * 16;
            __builtin_amdgcn_global_load_lds(
                (cg_void*)(const void*)&Wt[(size_t)(n0 + rbase + lr4) * ldW + kbase + kt + gcg * 8],
                (lds_void*)(void*)&Bs[buf][rbase * 32], 16, 0, 0);
        }
    };
    // compute one half: 32 (or 16) MFMA; frag colgroup = quad ^ (row&3)
    auto compute = [&](int buf) {
        const int swz = l16 & 3;
        short8 a[MF], b[NF];
#pragma unroll
        for (int mf = 0; mf < MF; mf++)
            a[mf] = *(const short8*)&As[buf][(wr * (MF * 16) + mf * 16 + l16) * 32 +
                     ((quad ^ swz) * 8)];
#pragma unroll
        for (int nf = 0; nf < NF; nf++)
            b[nf] = *(const short8*)&Bs[buf][(wc * 64 + nf * 16 + l16) * 32 +
                     ((quad ^ swz) * 8)];
#pragma unroll
        for (int mf = 0; mf < MF; mf++)
#pragma unroll
            for (int nf = 0; nf < NF; nf++)
                acc[mf][nf] = __builtin_amdgcn_mfma_f32_16x16x32_bf16(
                    a[mf], b[nf], acc[mf][nf], 0, 0, 0);
    };

    const int NH = Kd >> 5;                        // BK=32 halves; >=16 always
    stage(0, 0);
    stage(1, 32);
    stage(2, 64);
    int bc = 0, bs = 3;
    for (int it = 0; it < NH; ++it) {
        if (it + 3 < NH) {
            stage(bs, (it + 3) * 32);
            if (++bs == 4) bs = 0;
        }
        const int rem = (NH - 1 - it) < 3 ? (NH - 1 - it) : 3;
        if (rem == 3) {
            if constexpr (LD == 4) asm volatile("s_waitcnt vmcnt(12)" ::: "memory");
            else                   asm volatile("s_waitcnt vmcnt(9)"  ::: "memory");
        } else if (rem == 2) {
            if constexpr (LD == 4) asm volatile("s_waitcnt vmcnt(8)"  ::: "memory");
            else                   asm volatile("s_waitcnt vmcnt(6)"  ::: "memory");
        } else if (rem == 1) {
            if constexpr (LD == 4) asm volatile("s_waitcnt vmcnt(4)"  ::: "memory");
            else                   asm volatile("s_waitcnt vmcnt(3)"  ::: "memory");
        } else {
            asm volatile("s_waitcnt vmcnt(0)" ::: "memory");
        }
        __builtin_amdgcn_s_barrier();              // half `it` visible to all
        __builtin_amdgcn_s_setprio(1);
        compute(bc);
        __builtin_amdgcn_s_setprio(0);
        if (++bc == 4) bc = 0;
        asm volatile("s_waitcnt lgkmcnt(0)" ::: "memory");  // WAR fence
        __builtin_amdgcn_s_barrier();              // buffer reusable
    }

    const float qscale = (SCQ && n0 < 1024) ? QSC : 1.0f;
#pragma unroll
    for (int mf = 0; mf < MF; mf++) {
#pragma unroll
        for (int r = 0; r < 4; r++) {
            const int gm = m0 + wr * (MF * 16) + mf * 16 + quad * 4 + r;
#pragma unroll
            for (int nf = 0; nf < NF; nf++) {
                const int gn = n0 + wc * 64 + nf * 16 + l16;
                const int cn = SPLITC ? (gn & 2047) : gn;
                float c = acc[mf][nf][r];
                if (HAS_BIAS) c += bias[gn];
                if (RELU) c = fmaxf(c, 0.f);
                if (SCQ) c *= qscale;
                if (ATOM) {
                    atomicAdd(&outF[(size_t)gm * ldC + gn], c);
                } else {
                    u16* Cp = (SPLITC && gn >= 2048) ? Cout2 : Cout;
                    Cp[(size_t)gm * ldC + cn] = f2bf(c);
                }
            }
        }
    }
}

// ---------------- small-tile GEMM (O-proj only): R0 structure ----------------
template<int TM, int HAS_BIAS, int RELU, int RES, int OUT_F32, int SCQ,
         int SPLITC, int SPLITA, int ATOM = 0, int XSWZ = 0, int PIPE = 0>
__global__ __launch_bounds__(256)
void gemm_bt(const u16* __restrict__ A, const u16* __restrict__ A2, int ldA,
             const u16* __restrict__ Wt, int ldW,
             const float* __restrict__ bias, const void* __restrict__ res,
             void* __restrict__ Cout, void* __restrict__ Cout2,
             int ldC, int Kd) {
    constexpr int IF = TM / 32;          // i-frags per wave
    constexpr int RB = 1;
    __shared__ __align__(16) u16 As[RB][TM * 32];
    __shared__ __align__(16) u16 Bs[RB][128 * 32];
    const int tid  = threadIdx.x;
    const int lane = tid & 63, wv = tid >> 6;
    const int quad = lane >> 4, l16 = lane & 15;

    int bx = blockIdx.x, by = blockIdx.y, bz = blockIdx.z;
    if (XSWZ) {
        const int GX = gridDim.x, GY = gridDim.y;
        const int L = (bz * GY + by) * GX + bx;   // hw dispatch order
        const int xcd = L & 7, slot = L >> 3;
        const int p = slot / GX;                  // panel index on this XCD
        bx = slot - p * GX;                       // x sweeps consecutively
        const int yz = p * 8 + xcd;               // (y,z) panel, XCD-resident
        by = yz & (GY - 1);
        bz = yz >> __builtin_ctz(GY);
    }

    const int m0 = by * TM, n0 = bx * 128;
    const int rw = (wv >> 1) * (TM / 2), cw = (wv & 1) * 64;
    const int lr  = lane >> 2;                         // row within 16-row chunk
    const int gsw = ((lane & 3) ^ ((lane >> 3) & 3)) * 8;  // swizzled src colgrp
    const int psw = (quad ^ ((l16 >> 1) & 3)) * 8;     // swizzled read colgrp

    f32x4 acc[IF][4] = {};

    auto stage = [&](int buf, int kt) {
        const u16* Ap = (SPLITA && kt >= 2048) ? A2 : A;
        const int  kk = SPLITA ? (kt & 2047) : kt;
#pragma unroll
        for (int t = 0; t < TM / 64; t++) {
            const int row = wv * (TM / 4) + t * 16;
            __builtin_amdgcn_global_load_lds(
                (cg_void*)(const void*)&Ap[(size_t)(m0 + row + lr) * ldA + kk + gsw],
                (lds_void*)(void*)&As[buf][row * 32], 16, 0, 0);
        }
#pragma unroll
        for (int t = 0; t < 2; t++) {
            const int row = wv * 32 + t * 16;
            __builtin_amdgcn_global_load_lds(
                (cg_void*)(const void*)&Wt[(size_t)(n0 + row + lr) * ldW + kt + gsw],
                (lds_void*)(void*)&Bs[buf][row * 32], 16, 0, 0);
        }
    };
    auto compute = [&](int buf) {
        short8 af[IF], bfr[4];
#pragma unroll
        for (int i = 0; i < IF; i++)
            af[i] = *(const short8*)&As[buf][(rw + i * 16 + l16) * 32 + psw];
#pragma unroll
        for (int j = 0; j < 4; j++)
            bfr[j] = *(const short8*)&Bs[buf][(cw + j * 16 + l16) * 32 + psw];
#pragma unroll
        for (int i = 0; i < IF; i++)
#pragma unroll
            for (int j = 0; j < 4; j++)
                acc[i][j] = __builtin_amdgcn_mfma_f32_16x16x32_bf16(
                    af[i], bfr[j], acc[i][j], 0, 0, 0);
    };

    const int kbase = ATOM ? bz * Kd : 0;
    for (int kt = kbase; kt < kbase + Kd; kt += 32) {
        __syncthreads();
        stage(0, kt);
        __syncthreads();
        compute(0);
    }

    const float qscale = (SCQ && n0 < 1024) ? QSC : 1.0f;
    void* Cp = (SPLITC && n0 >= 2048) ? Cout2 : Cout;
#pragma unroll
    for (int i = 0; i < IF; i++) {
#pragma unroll
        for (int r = 0; r < 4; r++) {
            const int gm = m0 + rw + i * 16 + quad * 4 + r;
#pragma unroll
            for (int j = 0; j < 4; j++) {
                const int gn = n0 + cw + j * 16 + l16;
                const int cn = SPLITC ? (gn & 2047) : gn;
                float c = acc[i][j][r];
                if (HAS_BIAS) c += bias[gn];
                if (RELU) c = fmaxf(c, 0.f);
                if (RES == 1) c += ((const float*)res)[(size_t)gm * ldC + cn];
                if (RES == 2) c += bf2f(((const u16*)res)[(size_t)gm * ldC + cn]);
                if (SCQ) c *= qscale;
                if (ATOM) {
                    atomicAdd(&((float*)Cp)[(size_t)gm * ldC + cn], c);
                } else if (OUT_F32) {
                    ((float*)Cp)[(size_t)gm * ldC + cn] = c;
                } else {
                    ((u16*)Cp)[(size_t)gm * ldC + cn] = f2bf(c);
                }
            }
        }
    }
}

// ---------------- Flash attention pass 1 (split-K) ---------------------------
__global__ __launch_bounds__(256)
void flash_pass1(const u16* __restrict__ QKV, const u16* __restrict__ Vg,
                 u16* __restrict__ Op0, u16* __restrict__ Op1qkv,
                 float* __restrict__ stats) {
    const int pr = blockIdx.x >> 1, half = blockIdx.x & 1;
    const int hh = blockIdx.y, bb = blockIdx.z;
    const int tid  = threadIdx.x;
    const int lane = tid & 63, wv = tid >> 6;
    const int quad = lane >> 4, l16 = lane & 15;

    __shared__ __align__(16) u16 Ks[2][64 * 64];
    __shared__ __align__(16) u16 Vt[2][64 * 64];
    __shared__ __align__(16) u16 Ps[4][16 * 64];

    const size_t rowbase = (size_t)(bb * Tn) * QKVLD;
    const u16* Vgh = Vg + (size_t)(bb * Hn + hh) * 64 * 2048;

    const int sr = tid >> 2;
    const int p0 = (tid & 3) | ((sr & 1) << 2);
    const int p1 = p0 ^ 4;
    const int g0 = p0 ^ (sr & 7), g1 = p1 ^ (sr & 7);
    const int lsw = l16 & 7;                       // fragment-read row swizzle

    uint4 kA, kB, vA, vB;
    auto prefetch = [&](int kt) {
        const size_t kb = rowbase + (size_t)(kt * 64 + sr) * QKVLD + 1024 + hh * 64;
        kA = *(const uint4*)&QKV[kb + g0 * 8];
        kB = *(const uint4*)&QKV[kb + g1 * 8];
        const size_t vb = (size_t)sr * 2048 + kt * 64;
        vA = *(const uint4*)&Vgh[vb + g0 * 8];
        vB = *(const uint4*)&Vgh[vb + g1 * 8];
    };
    auto writebuf = [&](int buf) {
        *(uint4*)&Ks[buf][sr * 64 + p0 * 8] = kA;
        *(uint4*)&Ks[buf][sr * 64 + p1 * 8] = kB;
        *(uint4*)&Vt[buf][sr * 64 + p0 * 8] = vA;
        *(uint4*)&Vt[buf][sr * 64 + p1 * 8] = vB;
    };

    for (int qsel = 0; qsel < 2; qsel++) {
        const int qt = qsel ? (31 - pr) : pr;
        const int nk = (qt >= half) ? ((qt - half) >> 1) + 1 : 0;
        const int qrow = qt * 64 + wv * 16 + l16;
        const int grow = bb * Tn + qrow;

        f32x4 ot[4] = {};
        float m2 = -INFINITY, lrow = 0.f;

        HBAR();
        if (nk > 0) {
            const u16* qp = QKV + rowbase + (size_t)qrow * QKVLD + hh * 64;
            short8 qf[2];
            qf[0] = *(const short8*)&qp[quad * 8];
            qf[1] = *(const short8*)&qp[32 + quad * 8];

            prefetch(half);
            writebuf(0);
            if (nk > 1) prefetch(half + 2);
            HBAR();

            const bool hasdiag = ((qt ^ half) & 1) == 0;
            for (int f = 0; f < nk; f++) {
                const int cur = f & 1;

                f32x4 st[4] = {};
#pragma unroll
                for (int ks = 0; ks < 2; ks++)
#pragma unroll
                    for (int i = 0; i < 4; i++) {
                        short8 kf = *(const short8*)&Ks[cur][(i * 16 + l16) * 64 +
                                     (((ks * 4 + quad) ^ lsw) * 8)];
                        st[i] = __builtin_amdgcn_mfma_f32_16x16x32_bf16(
                            kf, qf[ks], st[i], 0, 0, 0);
                    }

                float tmax = -INFINITY;
                if (hasdiag && f == nk - 1) {
                    const int qloc = wv * 16 + l16;
#pragma unroll
                    for (int i = 0; i < 4; i++)
#pragma unroll
                        for (int r = 0; r < 4; r++) {
                            float s = st[i][r];
                            if (i * 16 + quad * 4 + r > qloc) s = -INFINITY;
                            st[i][r] = s;
                            tmax = fmaxf(tmax, s);
                        }
                } else {
#pragma unroll
                    for (int i = 0; i < 4; i++)
#pragma unroll
                        for (int r = 0; r < 4; r++)
                            tmax = fmaxf(tmax, st[i][r]);
                }
                tmax = fmaxf(tmax, __shfl_xor(tmax, 16));
                tmax = fmaxf(tmax, __shfl_xor(tmax, 32));

                const float mnew = fmaxf(m2, tmax);
                const float alpha = exp2f(m2 - mnew);
                m2 = mnew;
                float psum = 0.f;
#pragma unroll
                for (int i = 0; i < 4; i++)
#pragma unroll
                    for (int r = 0; r < 4; r++) {
                        const float e = exp2f(st[i][r] - mnew);
                        st[i][r] = e;
                        psum += e;
                    }
                psum += __shfl_xor(psum, 16);
                psum += __shfl_xor(psum, 32);
                lrow = lrow * alpha + psum;
#pragma unroll
                for (int i = 0; i < 4; i++) ot[i] *= alpha;

#pragma unroll
                for (int i = 0; i < 4; i++) {
                    uint2 w;
                    w.x = (u32)f2bf(st[i][0]) | ((u32)f2bf(st[i][1]) << 16);
                    w.y = (u32)f2bf(st[i][2]) | ((u32)f2bf(st[i][3]) << 16);
                    const int g = (i * 2 + (quad >> 1)) ^ lsw;
                    *(uint2*)&Ps[wv][l16 * 64 + g * 8 + (quad & 1) * 4] = w;
                }
                asm volatile("s_waitcnt lgkmcnt(0)" ::: "memory");

#pragma unroll
                for (int ks = 0; ks < 2; ks++) {
                    short8 pf = *(const short8*)&Ps[wv][l16 * 64 +
                                 (((ks * 4 + quad) ^ lsw) * 8)];
#pragma unroll
                    for (int i = 0; i < 4; i++) {
                        short8 vf = *(const short8*)&Vt[cur][(i * 16 + l16) * 64 +
                                     (((ks * 4 + quad) ^ lsw) * 8)];
                        ot[i] = __builtin_amdgcn_mfma_f32_16x16x32_bf16(
                            vf, pf, ot[i], 0, 0, 0);
                    }
                }

                if (f + 1 < nk) {
                    writebuf(cur ^ 1);
                    if (f + 2 < nk) prefetch(half + 2 * (f + 2));
                    HBAR();
                }
            }
        }

        u16* op = (half == 0) ? (Op0 + (size_t)grow * 1024 + hh * 64)
                              : (Op1qkv + (size_t)grow * QKVLD + 2048 + hh * 64);
#pragma unroll
        for (int i = 0; i < 4; i++) {
            ushort4 o4;
            o4.x = f2bf(ot[i][0]); o4.y = f2bf(ot[i][1]);
            o4.z = f2bf(ot[i][2]); o4.w = f2bf(ot[i][3]);
            *(ushort4*)&op[i * 16 + quad * 4] = o4;
        }
        if (quad == 0) {
            stats[((size_t)(half * 2 + 0) * 4096 + grow) * 16 + hh] = m2;
            stats[((size_t)(half * 2 + 1) * 4096 + grow) * 16 + hh] = lrow;
        }
    }
}

// ---------------- Flash merge: O = (w0 Oa + w1 Ob) / (w0 l0 + w1 l1) ---------
__global__ __launch_bounds__(256)
void flash_merge(u16* __restrict__ QKV, const u16* __restrict__ Op0,
                 const float* __restrict__ stats) {
    const int row = blockIdx.x;
    const int tid = threadIdx.x;
    const int col = tid * 4;
    const int hh = col >> 6;
    const float m0 = stats[((size_t)0 * 4096 + row) * 16 + hh];
    const float l0 = stats[((size_t)1 * 4096 + row) * 16 + hh];
    const float m1 = stats[((size_t)2 * 4096 + row) * 16 + hh];
    const float l1 = stats[((size_t)3 * 4096 + row) * 16 + hh];
    const float m  = fmaxf(m0, m1);
    const float w0 = exp2f(m0 - m), w1 = exp2f(m1 - m);
    const float inv = 1.0f / (w0 * l0 + w1 * l1);
    ushort4 a = *(const ushort4*)&Op0[(size_t)row * 1024 + col];
    ushort4 b = *(const ushort4*)&QKV[(size_t)row * QKVLD + 2048 + col];
    ushort4 o;
    o.x = f2bf((w0 * bf2f(a.x) + w1 * bf2f(b.x)) * inv);
    o.y = f2bf((w0 * bf2f(a.y) + w1 * bf2f(b.y)) * inv);
    o.z = f2bf((w0 * bf2f(a.z) + w1 * bf2f(b.z)) * inv);
    o.w = f2bf((w0 * bf2f(a.w) + w1 * bf2f(b.w)) * inv);
    *(ushort4*)&QKV[(size_t)row * QKVLD + col] = o;
}

// ---------------- Launcher ---------------------------------------------------
// Inputs fp32, output fp32 [B,T,E].
extern "C" void kernel_launch(void* const* d_in, const int* in_sizes, int n_in,
                              void* d_out, int out_size, void* d_ws, size_t ws_size,
                              hipStream_t stream) {
    const float* x   = (const float*)d_in[0];
    const float* Wq  = (const float*)d_in[1];
    const float* Wk  = (const float*)d_in[2];
    const float* Wv  = (const float*)d_in[3];
    const float* Wo  = (const float*)d_in[4];
    const float* bo  = (const float*)d_in[5];
    const float* W1  = (const float*)d_in[6];
    const float* b1  = (const float*)d_in[7];
    const float* W2  = (const float*)d_in[8];
    const float* b2  = (const float*)d_in[9];
    const float* g1  = (const float*)d_in[10];
    const float* be1 = (const float*)d_in[11];
    const float* g2  = (const float*)d_in[12];
    const float* be2 = (const float*)d_in[13];

    // Workspace (40 MB):
    //   [ 0,24M): QKV bf16 [4096][3072]; after O-proj: F1a [0,16M) [4096][2048]
    //   [16,24M): W2T bf16 [1024][4096] (written after O-proj)
    //   [24,32M): Op0 bf16 [4096][1024]; later X1 bf16 (same slot)
    //   [32,40M): Vg [32][64][2048] (V^T per (b,h)); after flash: F1b [4096][2048]
    // d_out (16 MB fp32): [0,8M) h bf16; [8,16M): WqkvT(6M)+WoT(2M) early;
    //   stats (1M over dead WqkvT) during flash; W1T (8M) late.
    //   After FF1: whole d_out becomes the fp32 FF2 accumulator (init + atomics).
    char* wsb = (char*)d_ws;
    u16*   QKV = (u16*)wsb;
    u16*   F1a = (u16*)wsb;                              // [4096][2048]
    u16*   W2T = (u16*)(wsb + 16u * 1024 * 1024);        // [1024][4096]
    u16*   Op0 = (u16*)(wsb + 24u * 1024 * 1024);        // [4096][1024]
    u16*   X1b = Op0;                                    // X1 bf16, same slot
    u16*   Vg  = (u16*)(wsb + 32u * 1024 * 1024);        // [32][64][2048]
    u16*   F1b = Vg;                                     // [4096][2048]
    u16*   h     = (u16*)d_out;
    u16*   WT    = (u16*)((char*)d_out + 8u * 1024 * 1024);
    u16*   WqkvT = WT;                                   // [3072][1024] (early)
    u16*   WoT   = WT + 3u * 1024 * 1024;                // [1024][1024]
    float* stats = (float*)WT;                           // 1 MB (over dead WqkvT)
    u16*   W1T   = WT;                                   // [4096][1024] (late)

    // 0. early weight transposes (fp32 -> bf16, B^T layout)
    transpose_w4<<<dim3(16, 16, 4), 256, 0, stream>>>(
        Wq, Wk, Wv, Wo,
        WqkvT, WqkvT + 1024u * 1024, WqkvT + 2048u * 1024, WoT);

    // 1. h = LN(x, g1, be1)
    ln_kernel<float><<<Mn, 256, 0, stream>>>(x, g1, be1, h);

    // 2. QKV = h @ [Wq|Wk|Wv]; Q pre-scaled  (ring-4 256x256 + XCD swizzle)
    gemm256<256, 0, 0, 0, 1, 0, 0, 1><<<dim3(12, 16), 512, 0, stream>>>(
        h, nullptr, En, WqkvT, En, nullptr, QKV, nullptr, nullptr, QKVLD, En);

    // 3. Vg = V^T per (b,h)
    vcopy_t<<<dim3(1, 32, 32), 256, 0, stream>>>(QKV, Vg);

    // 4. split-K flash pass 1 -> partials + stats  (1024 blocks, 4/CU)
    flash_pass1<<<dim3(32, Hn, Bn), 256, 0, stream>>>(QKV, Vg, Op0, QKV, stats);

    // 5. merge partials -> O into QKV cols [0,1024)
    flash_merge<<<Mn, 256, 0, stream>>>(QKV, Op0, stats);

    // 6. X1 = x + O @ Wo + bo  (128-family R0-structure, 12 KB LDS)
    gemm_bt<64, 1, 0, 1, 0, 0, 0, 0, 0, 1, 0><<<dim3(8, 64), 256, 0, stream>>>(
        QKV, nullptr, QKVLD, WoT, En, bo, x, X1b, nullptr, En, En);

    // 7. late weight transposes (QKV + WT + Vg regions now dead)
    transpose_w<<<dim3(64, 16), 256, 0, stream>>>(W1, W1T, 1024, 4096);
    transpose_w<<<dim3(16, 64), 256, 0, stream>>>(W2, W2T, 4096, 1024);

    // 8. h2 = LN(X1, g2, be2)
    ln_kernel<u16><<<Mn, 256, 0, stream>>>(X1b, g2, be2, h);

    // 9. FF1: relu(h2 @ W1 + b1) -> F1a/F1b  (ring-4 256x256 + XCD swizzle)
    gemm256<256, 1, 1, 1, 0, 0, 0, 1><<<dim3(16, 16), 512, 0, stream>>>(
        h, nullptr, En, W1T, En, b1, F1a, F1b, nullptr, 2048, En);

    // 9.5. init FF2 accumulator: d_out = X1 + b2 (fp32)
    ff2_init<<<Mn, 256, 0, stream>>>(X1b, b2, (float*)d_out);

    // 10. FF2: ring-4 256x128, split-K=2 atomic + XCD swizzle.
    gemm256<128, 0, 0, 0, 0, 1, 1, 1><<<dim3(8, 16, 2), 512, 0, stream>>>(
        F1a, F1b, 2048, W2T, DFFn, nullptr, nullptr, nullptr,
        (float*)d_out, En, 2048);
}

// Round 16
// 396.696 us; speedup vs baseline: 1.0119x; 1.0119x over previous
//
#include <hip/hip_runtime.h>
#include <hip/hip_bf16.h>
#include <math.h>

// Problem constants
#define Bn 2
#define Tn 2048
#define En 1024
#define Hn 16
#define DFFn 4096
#define Mn (Bn*Tn)   // 4096 rows
#define QKVLD 3072   // fused QKV leading dim

typedef __hip_bfloat16 bf16;
typedef unsigned short u16;
typedef unsigned int u32;
typedef __attribute__((ext_vector_type(8))) short short8;
typedef __attribute__((ext_vector_type(4))) float f32x4;

typedef __attribute__((address_space(1))) const void cg_void;
typedef __attribute__((address_space(3))) void lds_void;

// Q pre-scale folded into QKV GEMM: E^-0.5 * log2(e)
#define QSC 0.0450842200278f

// lgkm-only barrier: LDS writes visible + wave sync; vmcnt (global loads in
// flight to wave-private registers) NOT drained -- prefetches survive it.
#define HBAR() asm volatile("s_waitcnt lgkmcnt(0)\n\ts_barrier" ::: "memory")

__device__ __forceinline__ u16 f2bf(float f) {
    bf16 h = __float2bfloat16(f);
    u16 u; __builtin_memcpy(&u, &h, 2); return u;
}
__device__ __forceinline__ float bf2f(u16 u) {
    u32 x = ((u32)u) << 16; float f; __builtin_memcpy(&f, &x, 4); return f;
}

// ---------------- 4x weight transpose+convert (1024x1024 each) ---------------
__global__ __launch_bounds__(256)
void transpose_w4(const float* __restrict__ s0, const float* __restrict__ s1,
                  const float* __restrict__ s2, const float* __restrict__ s3,
                  u16* __restrict__ d0, u16* __restrict__ d1,
                  u16* __restrict__ d2, u16* __restrict__ d3) {
    const float* src = (blockIdx.z == 0) ? s0 : (blockIdx.z == 1) ? s1
                     : (blockIdx.z == 2) ? s2 : s3;
    u16* dst = (blockIdx.z == 0) ? d0 : (blockIdx.z == 1) ? d1
             : (blockIdx.z == 2) ? d2 : d3;
    __shared__ float t[64][65];
    const int r0 = blockIdx.y * 64, c0 = blockIdx.x * 64;
    const int tr = threadIdx.x >> 6, tc = threadIdx.x & 63;
#pragma unroll
    for (int i = 0; i < 16; i++)
        t[tr + i * 4][tc] = src[(size_t)(r0 + tr + i * 4) * 1024 + c0 + tc];
    __syncthreads();
#pragma unroll
    for (int i = 0; i < 16; i++)
        dst[(size_t)(c0 + tr + i * 4) * 1024 + r0 + tc] = f2bf(t[tc][tr + i * 4]);
}

// ---------------- generic weight transpose: src fp32 [R][C] -> bf16 [C][R] ---
__global__ __launch_bounds__(256)
void transpose_w(const float* __restrict__ src, u16* __restrict__ dst,
                 int R, int C) {
    __shared__ float t[64][65];
    const int r0 = blockIdx.y * 64, c0 = blockIdx.x * 64;
    const int tr = threadIdx.x >> 6, tc = threadIdx.x & 63;
#pragma unroll
    for (int i = 0; i < 16; i++)
        t[tr + i * 4][tc] = src[(size_t)(r0 + tr + i * 4) * C + c0 + tc];
    __syncthreads();
#pragma unroll
    for (int i = 0; i < 16; i++)
        dst[(size_t)(c0 + tr + i * 4) * R + r0 + tc] = f2bf(t[tc][tr + i * 4]);
}

// ---------------- V copy-transpose: QKV V-cols -> Vg[bh][dh=64][tok=2048] ----
__global__ __launch_bounds__(256)
void vcopy_t(const u16* __restrict__ QKV, u16* __restrict__ Vg) {
    const int bh = blockIdx.z;          // bb*16+hh
    const int t0 = blockIdx.y * 64;     // token tile
    __shared__ u16 t[64][65];
    const int tr = threadIdx.x >> 6, tc = threadIdx.x & 63;
    const u16* src = QKV + (size_t)(bh >> 4) * 2048 * QKVLD + 2048 + (bh & 15) * 64;
#pragma unroll
    for (int i = 0; i < 16; i++)
        t[tr + i * 4][tc] = src[(size_t)(t0 + tr + i * 4) * QKVLD + tc];  // [tokl][dh]
    __syncthreads();
    u16* dst = Vg + (size_t)bh * 64 * 2048;
#pragma unroll
    for (int i = 0; i < 16; i++)
        dst[(size_t)(tr + i * 4) * 2048 + t0 + tc] = t[tc][tr + i * 4];
}

// ---------------- LayerNorm: one block per row of E=1024 ---------------------
template<typename AT>
__global__ __launch_bounds__(256)
void ln_kernel(const AT* __restrict__ x, const float* __restrict__ g,
               const float* __restrict__ b, u16* __restrict__ out) {
    const int row = blockIdx.x;
    const int tid = threadIdx.x;
    const AT* xp = x + (size_t)row * En;
    float v[4];
    float s = 0.f, sq = 0.f;
#pragma unroll
    for (int i = 0; i < 4; i++) {
        if constexpr (sizeof(AT) == 2) v[i] = bf2f(xp[tid + i * 256]);
        else                           v[i] = (float)xp[tid + i * 256];
        s += v[i];
        sq += v[i] * v[i];
    }
    __shared__ float rs[256], rq[256];
    rs[tid] = s; rq[tid] = sq;
    __syncthreads();
    for (int st = 128; st > 0; st >>= 1) {
        if (tid < st) { rs[tid] += rs[tid + st]; rq[tid] += rq[tid + st]; }
        __syncthreads();
    }
    const float mu  = rs[0] * (1.0f / En);
    const float var = rq[0] * (1.0f / En) - mu * mu;
    const float inv = rsqrtf(var + 1e-5f);
#pragma unroll
    for (int i = 0; i < 4; i++) {
        const int c = tid + i * 256;
        out[(size_t)row * En + c] = f2bf((v[i] - mu) * inv * g[c] + b[c]);
    }
}

// ---------------- FF2 output init: out = X1(bf16) + b2 (fp32) ----------------
__global__ __launch_bounds__(256)
void ff2_init(const u16* __restrict__ X1, const float* __restrict__ b2,
              float* __restrict__ out) {
    const int row = blockIdx.x;
    const int c = threadIdx.x * 4;
    ushort4 a = *(const ushort4*)&X1[(size_t)row * En + c];
    float4 bb = *(const float4*)&b2[c];
    float4 o;
    o.x = bf2f(a.x) + bb.x;
    o.y = bf2f(a.y) + bb.y;
    o.z = bf2f(a.z) + bb.z;
    o.w = bf2f(a.w) + bb.w;
    *(float4*)&out[(size_t)row * En + c] = o;
}

// ---------------- 256xTN ring-4 counted-vmcnt GEMM ---------------------------
// C[M,N] = A(bf16 [M][K]) @ Wt(bf16 [N][K])^T. 256(M) x TN(N) tile, 512 thr
// (8 waves; TN=256: 2Mx4N, per-wave 128x64; TN=128: 4Mx2N, per-wave 64x64).
// T3+T4+T5: BK=32 half-tiles in a ring of 4 LDS buffers. Stage half t+3
// while computing half t; vmcnt(3*LD) proves half t landed (in-order
// retirement); lgkmcnt(0) before the release barrier (WAR); setprio(1)
// around the MFMA cluster.
// R16 BANK-CONFLICT FIX: BK=32 rows are 64 B (16 banks), so row bank-phase
// = row&1 only. R15's swizzle quad^(l16&3) made lanes {0,4,8,12} share one
// 4-bank slot -> 4-way conflict (4.2M counted, FF2 68->82 us). New swizzle
// uses row bits 1-2: read slot = quad ^ ((row>>1)&3); stage places global
// cg (l&3)^((l>>3)&3) at slot l&3 (same involution both sides). Slot walk
// (4*l16 + quad^((l16>>1)&3)) mod 8 covers all 8 slots exactly 2x over 16
// lanes -> 2-way aliasing = free (m136).
// XSWZ: panel-per-XCD remap (FF2 FETCH 135->49 MB). panel by -> XCD by&7
// at all sites (GY=16); FF2 z-pair shares XCD.
// ATOM: split-K over gridDim.z, fp32 atomicAdd into pre-init'd outF.
// SPLITA: slice z reads A (z==0) or A2 (z==1), local cols [0,Kd).
template<int TN, int HAS_BIAS, int RELU, int SPLITC, int SCQ, int ATOM,
         int SPLITA, int XSWZ>
__global__ __launch_bounds__(512, 2)
void gemm256(const u16* __restrict__ A, const u16* __restrict__ A2, int ldA,
             const u16* __restrict__ Wt, int ldW,
             const float* __restrict__ bias,
             u16* __restrict__ Cout, u16* __restrict__ Cout2,
             float* __restrict__ outF, int ldC, int Kd) {
    constexpr int WGN = (TN == 256) ? 4 : 2;       // waves along N
    constexpr int MF  = (256 / (8 / WGN)) / 16;    // m-frags/wave: 8 or 4
    constexpr int NF  = (TN / WGN) / 16;           // n-frags/wave: 4
    constexpr int LD  = 2 + TN / 128;              // gload_lds per wave/half
    __shared__ __align__(16) u16 As[4][256 * 32];
    __shared__ __align__(16) u16 Bs[4][TN * 32];
    const int tid  = threadIdx.x;
    const int lane = tid & 63, wv = tid >> 6;      // 8 waves
    const int quad = lane >> 4, l16 = lane & 15;
    const int wr = wv / WGN, wc = wv % WGN;
    const int lr4 = lane >> 2;                     // row within 16-row group
    const int gcg = (lane & 3) ^ ((lane >> 3) & 3);  // src colgroup (FIXED)

    int bx = blockIdx.x, by = blockIdx.y, bz = blockIdx.z;
    if (XSWZ) {
        const int GX = gridDim.x, GY = gridDim.y;  // GY == 16 at all sites
        const int L = (bz * GY + by) * GX + bx;    // hw dispatch order
        const int xcd = L & 7, slot = L >> 3;
        const int p = slot / GX;                   // panel index on this XCD
        bx = slot - p * GX;                        // x sweeps consecutively
        const int yz = p * 8 + xcd;                // (y,z) panel, XCD-resident
        by = yz & (GY - 1);
        bz = yz >> 4;                              // GY=16
    }

    const int m0 = by * 256, n0 = bx * TN;
    const u16* Ap = (SPLITA && ATOM && bz) ? A2 : A;
    const int kbase = ATOM ? bz * Kd : 0;          // B-side global K offset

    f32x4 acc[MF][NF] = {};

    // stage one BK=32 half-tile: per wave-load 64 lanes x 16B = 16 rows x 32
    auto stage = [&](int buf, int kt) {            // kt = local A col (32-mult)
#pragma unroll
        for (int i = 0; i < 2; i++) {              // A: 256 rows = 2 x 128
            const int rbase = i * 128 + wv * 16;
            __builtin_amdgcn_global_load_lds(
                (cg_void*)(const void*)&Ap[(size_t)(m0 + rbase + lr4) * ldA + kt + gcg * 8],
                (lds_void*)(void*)&As[buf][rbase * 32], 16, 0, 0);
        }
#pragma unroll
        for (int i = 0; i < TN / 128; i++) {       // B: TN rows
            const int rbase = i * 128 + wv * 16;
            __builtin_amdgcn_global_load_lds(
                (cg_void*)(const void*)&Wt[(size_t)(n0 + rbase + lr4) * ldW + kbase + kt + gcg * 8],
                (lds_void*)(void*)&Bs[buf][rbase * 32], 16, 0, 0);
        }
    };
    // compute one half; frag read slot = quad ^ ((row>>1)&3)  (FIXED)
    auto compute = [&](int buf) {
        const int swz = (l16 >> 1) & 3;
        short8 a[MF], b[NF];
#pragma unroll
        for (int mf = 0; mf < MF; mf++)
            a[mf] = *(const short8*)&As[buf][(wr * (MF * 16) + mf * 16 + l16) * 32 +
                     ((quad ^ swz) * 8)];
#pragma unroll
        for (int nf = 0; nf < NF; nf++)
            b[nf] = *(const short8*)&Bs[buf][(wc * 64 + nf * 16 + l16) * 32 +
                     ((quad ^ swz) * 8)];
#pragma unroll
        for (int mf = 0; mf < MF; mf++)
#pragma unroll
            for (int nf = 0; nf < NF; nf++)
                acc[mf][nf] = __builtin_amdgcn_mfma_f32_16x16x32_bf16(
                    a[mf], b[nf], acc[mf][nf], 0, 0, 0);
    };

    const int NH = Kd >> 5;                        // BK=32 halves; >=16 always
    stage(0, 0);
    stage(1, 32);
    stage(2, 64);
    int bc = 0, bs = 3;
    for (int it = 0; it < NH; ++it) {
        if (it + 3 < NH) {
            stage(bs, (it + 3) * 32);
            if (++bs == 4) bs = 0;
        }
        const int rem = (NH - 1 - it) < 3 ? (NH - 1 - it) : 3;
        if (rem == 3) {
            if constexpr (LD == 4) asm volatile("s_waitcnt vmcnt(12)" ::: "memory");
            else                   asm volatile("s_waitcnt vmcnt(9)"  ::: "memory");
        } else if (rem == 2) {
            if constexpr (LD == 4) asm volatile("s_waitcnt vmcnt(8)"  ::: "memory");
            else                   asm volatile("s_waitcnt vmcnt(6)"  ::: "memory");
        } else if (rem == 1) {
            if constexpr (LD == 4) asm volatile("s_waitcnt vmcnt(4)"  ::: "memory");
            else                   asm volatile("s_waitcnt vmcnt(3)"  ::: "memory");
        } else {
            asm volatile("s_waitcnt vmcnt(0)" ::: "memory");
        }
        __builtin_amdgcn_s_barrier();              // half `it` visible to all
        __builtin_amdgcn_s_setprio(1);
        compute(bc);
        __builtin_amdgcn_s_setprio(0);
        if (++bc == 4) bc = 0;
        asm volatile("s_waitcnt lgkmcnt(0)" ::: "memory");  // WAR fence
        __builtin_amdgcn_s_barrier();              // buffer reusable
    }

    const float qscale = (SCQ && n0 < 1024) ? QSC : 1.0f;
#pragma unroll
    for (int mf = 0; mf < MF; mf++) {
#pragma unroll
        for (int r = 0; r < 4; r++) {
            const int gm = m0 + wr * (MF * 16) + mf * 16 + quad * 4 + r;
#pragma unroll
            for (int nf = 0; nf < NF; nf++) {
                const int gn = n0 + wc * 64 + nf * 16 + l16;
                const int cn = SPLITC ? (gn & 2047) : gn;
                float c = acc[mf][nf][r];
                if (HAS_BIAS) c += bias[gn];
                if (RELU) c = fmaxf(c, 0.f);
                if (SCQ) c *= qscale;
                if (ATOM) {
                    atomicAdd(&outF[(size_t)gm * ldC + gn], c);
                } else {
                    u16* Cp = (SPLITC && gn >= 2048) ? Cout2 : Cout;
                    Cp[(size_t)gm * ldC + cn] = f2bf(c);
                }
            }
        }
    }
}

// ---------------- small-tile GEMM (O-proj only): R0 structure ----------------
template<int TM, int HAS_BIAS, int RELU, int RES, int OUT_F32, int SCQ,
         int SPLITC, int SPLITA, int ATOM = 0, int XSWZ = 0, int PIPE = 0>
__global__ __launch_bounds__(256)
void gemm_bt(const u16* __restrict__ A, const u16* __restrict__ A2, int ldA,
             const u16* __restrict__ Wt, int ldW,
             const float* __restrict__ bias, const void* __restrict__ res,
             void* __restrict__ Cout, void* __restrict__ Cout2,
             int ldC, int Kd) {
    constexpr int IF = TM / 32;          // i-frags per wave
    constexpr int RB = 1;
    __shared__ __align__(16) u16 As[RB][TM * 32];
    __shared__ __align__(16) u16 Bs[RB][128 * 32];
    const int tid  = threadIdx.x;
    const int lane = tid & 63, wv = tid >> 6;
    const int quad = lane >> 4, l16 = lane & 15;

    int bx = blockIdx.x, by = blockIdx.y, bz = blockIdx.z;
    if (XSWZ) {
        const int GX = gridDim.x, GY = gridDim.y;
        const int L = (bz * GY + by) * GX + bx;   // hw dispatch order
        const int xcd = L & 7, slot = L >> 3;
        const int p = slot / GX;                  // panel index on this XCD
        bx = slot - p * GX;                       // x sweeps consecutively
        const int yz = p * 8 + xcd;               // (y,z) panel, XCD-resident
        by = yz & (GY - 1);
        bz = yz >> __builtin_ctz(GY);
    }

    const int m0 = by * TM, n0 = bx * 128;
    const int rw = (wv >> 1) * (TM / 2), cw = (wv & 1) * 64;
    const int lr  = lane >> 2;                         // row within 16-row chunk
    const int gsw = ((lane & 3) ^ ((lane >> 3) & 3)) * 8;  // swizzled src colgrp
    const int psw = (quad ^ ((l16 >> 1) & 3)) * 8;     // swizzled read colgrp

    f32x4 acc[IF][4] = {};

    auto stage = [&](int buf, int kt) {
        const u16* Ap = (SPLITA && kt >= 2048) ? A2 : A;
        const int  kk = SPLITA ? (kt & 2047) : kt;
#pragma unroll
        for (int t = 0; t < TM / 64; t++) {
            const int row = wv * (TM / 4) + t * 16;
            __builtin_amdgcn_global_load_lds(
                (cg_void*)(const void*)&Ap[(size_t)(m0 + row + lr) * ldA + kk + gsw],
                (lds_void*)(void*)&As[buf][row * 32], 16, 0, 0);
        }
#pragma unroll
        for (int t = 0; t < 2; t++) {
            const int row = wv * 32 + t * 16;
            __builtin_amdgcn_global_load_lds(
                (cg_void*)(const void*)&Wt[(size_t)(n0 + row + lr) * ldW + kt + gsw],
                (lds_void*)(void*)&Bs[buf][row * 32], 16, 0, 0);
        }
    };
    auto compute = [&](int buf) {
        short8 af[IF], bfr[4];
#pragma unroll
        for (int i = 0; i < IF; i++)
            af[i] = *(const short8*)&As[buf][(rw + i * 16 + l16) * 32 + psw];
#pragma unroll
        for (int j = 0; j < 4; j++)
            bfr[j] = *(const short8*)&Bs[buf][(cw + j * 16 + l16) * 32 + psw];
#pragma unroll
        for (int i = 0; i < IF; i++)
#pragma unroll
            for (int j = 0; j < 4; j++)
                acc[i][j] = __builtin_amdgcn_mfma_f32_16x16x32_bf16(
                    af[i], bfr[j], acc[i][j], 0, 0, 0);
    };

    const int kbase = ATOM ? bz * Kd : 0;
    for (int kt = kbase; kt < kbase + Kd; kt += 32) {
        __syncthreads();
        stage(0, kt);
        __syncthreads();
        compute(0);
    }

    const float qscale = (SCQ && n0 < 1024) ? QSC : 1.0f;
    void* Cp = (SPLITC && n0 >= 2048) ? Cout2 : Cout;
#pragma unroll
    for (int i = 0; i < IF; i++) {
#pragma unroll
        for (int r = 0; r < 4; r++) {
            const int gm = m0 + rw + i * 16 + quad * 4 + r;
#pragma unroll
            for (int j = 0; j < 4; j++) {
                const int gn = n0 + cw + j * 16 + l16;
                const int cn = SPLITC ? (gn & 2047) : gn;
                float c = acc[i][j][r];
                if (HAS_BIAS) c += bias[gn];
                if (RELU) c = fmaxf(c, 0.f);
                if (RES == 1) c += ((const float*)res)[(size_t)gm * ldC + cn];
                if (RES == 2) c += bf2f(((const u16*)res)[(size_t)gm * ldC + cn]);
                if (SCQ) c *= qscale;
                if (ATOM) {
                    atomicAdd(&((float*)Cp)[(size_t)gm * ldC + cn], c);
                } else if (OUT_F32) {
                    ((float*)Cp)[(size_t)gm * ldC + cn] = c;
                } else {
                    ((u16*)Cp)[(size_t)gm * ldC + cn] = f2bf(c);
                }
            }
        }
    }
}

// ---------------- Flash attention pass 1 (split-K) ---------------------------
__global__ __launch_bounds__(256)
void flash_pass1(const u16* __restrict__ QKV, const u16* __restrict__ Vg,
                 u16* __restrict__ Op0, u16* __restrict__ Op1qkv,
                 float* __restrict__ stats) {
    const int pr = blockIdx.x >> 1, half = blockIdx.x & 1;
    const int hh = blockIdx.y, bb = blockIdx.z;
    const int tid  = threadIdx.x;
    const int lane = tid & 63, wv = tid >> 6;
    const int quad = lane >> 4, l16 = lane & 15;

    __shared__ __align__(16) u16 Ks[2][64 * 64];
    __shared__ __align__(16) u16 Vt[2][64 * 64];
    __shared__ __align__(16) u16 Ps[4][16 * 64];

    const size_t rowbase = (size_t)(bb * Tn) * QKVLD;
    const u16* Vgh = Vg + (size_t)(bb * Hn + hh) * 64 * 2048;

    const int sr = tid >> 2;
    const int p0 = (tid & 3) | ((sr & 1) << 2);
    const int p1 = p0 ^ 4;
    const int g0 = p0 ^ (sr & 7), g1 = p1 ^ (sr & 7);
    const int lsw = l16 & 7;                       // fragment-read row swizzle

    uint4 kA, kB, vA, vB;
    auto prefetch = [&](int kt) {
        const size_t kb = rowbase + (size_t)(kt * 64 + sr) * QKVLD + 1024 + hh * 64;
        kA = *(const uint4*)&QKV[kb + g0 * 8];
        kB = *(const uint4*)&QKV[kb + g1 * 8];
        const size_t vb = (size_t)sr * 2048 + kt * 64;
        vA = *(const uint4*)&Vgh[vb + g0 * 8];
        vB = *(const uint4*)&Vgh[vb + g1 * 8];
    };
    auto writebuf = [&](int buf) {
        *(uint4*)&Ks[buf][sr * 64 + p0 * 8] = kA;
        *(uint4*)&Ks[buf][sr * 64 + p1 * 8] = kB;
        *(uint4*)&Vt[buf][sr * 64 + p0 * 8] = vA;
        *(uint4*)&Vt[buf][sr * 64 + p1 * 8] = vB;
    };

    for (int qsel = 0; qsel < 2; qsel++) {
        const int qt = qsel ? (31 - pr) : pr;
        const int nk = (qt >= half) ? ((qt - half) >> 1) + 1 : 0;
        const int qrow = qt * 64 + wv * 16 + l16;
        const int grow = bb * Tn + qrow;

        f32x4 ot[4] = {};
        float m2 = -INFINITY, lrow = 0.f;

        HBAR();
        if (nk > 0) {
            const u16* qp = QKV + rowbase + (size_t)qrow * QKVLD + hh * 64;
            short8 qf[2];
            qf[0] = *(const short8*)&qp[quad * 8];
            qf[1] = *(const short8*)&qp[32 + quad * 8];

            prefetch(half);
            writebuf(0);
            if (nk > 1) prefetch(half + 2);
            HBAR();

            const bool hasdiag = ((qt ^ half) & 1) == 0;
            for (int f = 0; f < nk; f++) {
                const int cur = f & 1;

                f32x4 st[4] = {};
#pragma unroll
                for (int ks = 0; ks < 2; ks++)
#pragma unroll
                    for (int i = 0; i < 4; i++) {
                        short8 kf = *(const short8*)&Ks[cur][(i * 16 + l16) * 64 +
                                     (((ks * 4 + quad) ^ lsw) * 8)];
                        st[i] = __builtin_amdgcn_mfma_f32_16x16x32_bf16(
                            kf, qf[ks], st[i], 0, 0, 0);
                    }

                float tmax = -INFINITY;
                if (hasdiag && f == nk - 1) {
                    const int qloc = wv * 16 + l16;
#pragma unroll
                    for (int i = 0; i < 4; i++)
#pragma unroll
                        for (int r = 0; r < 4; r++) {
                            float s = st[i][r];
                            if (i * 16 + quad * 4 + r > qloc) s = -INFINITY;
                            st[i][r] = s;
                            tmax = fmaxf(tmax, s);
                        }
                } else {
#pragma unroll
                    for (int i = 0; i < 4; i++)
#pragma unroll
                        for (int r = 0; r < 4; r++)
                            tmax = fmaxf(tmax, st[i][r]);
                }
                tmax = fmaxf(tmax, __shfl_xor(tmax, 16));
                tmax = fmaxf(tmax, __shfl_xor(tmax, 32));

                const float mnew = fmaxf(m2, tmax);
                const float alpha = exp2f(m2 - mnew);
                m2 = mnew;
                float psum = 0.f;
#pragma unroll
                for (int i = 0; i < 4; i++)
#pragma unroll
                    for (int r = 0; r < 4; r++) {
                        const float e = exp2f(st[i][r] - mnew);
                        st[i][r] = e;
                        psum += e;
                    }
                psum += __shfl_xor(psum, 16);
                psum += __shfl_xor(psum, 32);
                lrow = lrow * alpha + psum;
#pragma unroll
                for (int i = 0; i < 4; i++) ot[i] *= alpha;

#pragma unroll
                for (int i = 0; i < 4; i++) {
                    uint2 w;
                    w.x = (u32)f2bf(st[i][0]) | ((u32)f2bf(st[i][1]) << 16);
                    w.y = (u32)f2bf(st[i][2]) | ((u32)f2bf(st[i][3]) << 16);
                    const int g = (i * 2 + (quad >> 1)) ^ lsw;
                    *(uint2*)&Ps[wv][l16 * 64 + g * 8 + (quad & 1) * 4] = w;
                }
                asm volatile("s_waitcnt lgkmcnt(0)" ::: "memory");

#pragma unroll
                for (int ks = 0; ks < 2; ks++) {
                    short8 pf = *(const short8*)&Ps[wv][l16 * 64 +
                                 (((ks * 4 + quad) ^ lsw) * 8)];
#pragma unroll
                    for (int i = 0; i < 4; i++) {
                        short8 vf = *(const short8*)&Vt[cur][(i * 16 + l16) * 64 +
                                     (((ks * 4 + quad) ^ lsw) * 8)];
                        ot[i] = __builtin_amdgcn_mfma_f32_16x16x32_bf16(
                            vf, pf, ot[i], 0, 0, 0);
                    }
                }

                if (f + 1 < nk) {
                    writebuf(cur ^ 1);
                    if (f + 2 < nk) prefetch(half + 2 * (f + 2));
                    HBAR();
                }
            }
        }

        u16* op = (half == 0) ? (Op0 + (size_t)grow * 1024 + hh * 64)
                              : (Op1qkv + (size_t)grow * QKVLD + 2048 + hh * 64);
#pragma unroll
        for (int i = 0; i < 4; i++) {
            ushort4 o4;
            o4.x = f2bf(ot[i][0]); o4.y = f2bf(ot[i][1]);
            o4.z = f2bf(ot[i][2]); o4.w = f2bf(ot[i][3]);
            *(ushort4*)&op[i * 16 + quad * 4] = o4;
        }
        if (quad == 0) {
            stats[((size_t)(half * 2 + 0) * 4096 + grow) * 16 + hh] = m2;
            stats[((size_t)(half * 2 + 1) * 4096 + grow) * 16 + hh] = lrow;
        }
    }
}

// ---------------- Flash merge: O = (w0 Oa + w1 Ob) / (w0 l0 + w1 l1) ---------
__global__ __launch_bounds__(256)
void flash_merge(u16* __restrict__ QKV, const u16* __restrict__ Op0,
                 const float* __restrict__ stats) {
    const int row = blockIdx.x;
    const int tid = threadIdx.x;
    const int col = tid * 4;
    const int hh = col >> 6;
    const float m0 = stats[((size_t)0 * 4096 + row) * 16 + hh];
    const float l0 = stats[((size_t)1 * 4096 + row) * 16 + hh];
    const float m1 = stats[((size_t)2 * 4096 + row) * 16 + hh];
    const float l1 = stats[((size_t)3 * 4096 + row) * 16 + hh];
    const float m  = fmaxf(m0, m1);
    const float w0 = exp2f(m0 - m), w1 = exp2f(m1 - m);
    const float inv = 1.0f / (w0 * l0 + w1 * l1);
    ushort4 a = *(const ushort4*)&Op0[(size_t)row * 1024 + col];
    ushort4 b = *(const ushort4*)&QKV[(size_t)row * QKVLD + 2048 + col];
    ushort4 o;
    o.x = f2bf((w0 * bf2f(a.x) + w1 * bf2f(b.x)) * inv);
    o.y = f2bf((w0 * bf2f(a.y) + w1 * bf2f(b.y)) * inv);
    o.z = f2bf((w0 * bf2f(a.z) + w1 * bf2f(b.z)) * inv);
    o.w = f2bf((w0 * bf2f(a.w) + w1 * bf2f(b.w)) * inv);
    *(ushort4*)&QKV[(size_t)row * QKVLD + col] = o;
}

// ---------------- Launcher ---------------------------------------------------
// Inputs fp32, output fp32 [B,T,E].
extern "C" void kernel_launch(void* const* d_in, const int* in_sizes, int n_in,
                              void* d_out, int out_size, void* d_ws, size_t ws_size,
                              hipStream_t stream) {
    const float* x   = (const float*)d_in[0];
    const float* Wq  = (const float*)d_in[1];
    const float* Wk  = (const float*)d_in[2];
    const float* Wv  = (const float*)d_in[3];
    const float* Wo  = (const float*)d_in[4];
    const float* bo  = (const float*)d_in[5];
    const float* W1  = (const float*)d_in[6];
    const float* b1  = (const float*)d_in[7];
    const float* W2  = (const float*)d_in[8];
    const float* b2  = (const float*)d_in[9];
    const float* g1  = (const float*)d_in[10];
    const float* be1 = (const float*)d_in[11];
    const float* g2  = (const float*)d_in[12];
    const float* be2 = (const float*)d_in[13];

    // Workspace (40 MB):
    //   [ 0,24M): QKV bf16 [4096][3072]; after O-proj: F1a [0,16M) [4096][2048]
    //   [16,24M): W2T bf16 [1024][4096] (written after O-proj)
    //   [24,32M): Op0 bf16 [4096][1024]; later X1 bf16 (same slot)
    //   [32,40M): Vg [32][64][2048] (V^T per (b,h)); after flash: F1b [4096][2048]
    // d_out (16 MB fp32): [0,8M) h bf16; [8,16M): WqkvT(6M)+WoT(2M) early;
    //   stats (1M over dead WqkvT) during flash; W1T (8M) late.
    //   After FF1: whole d_out becomes the fp32 FF2 accumulator (init + atomics).
    char* wsb = (char*)d_ws;
    u16*   QKV = (u16*)wsb;
    u16*   F1a = (u16*)wsb;                              // [4096][2048]
    u16*   W2T = (u16*)(wsb + 16u * 1024 * 1024);        // [1024][4096]
    u16*   Op0 = (u16*)(wsb + 24u * 1024 * 1024);        // [4096][1024]
    u16*   X1b = Op0;                                    // X1 bf16, same slot
    u16*   Vg  = (u16*)(wsb + 32u * 1024 * 1024);        // [32][64][2048]
    u16*   F1b = Vg;                                     // [4096][2048]
    u16*   h     = (u16*)d_out;
    u16*   WT    = (u16*)((char*)d_out + 8u * 1024 * 1024);
    u16*   WqkvT = WT;                                   // [3072][1024] (early)
    u16*   WoT   = WT + 3u * 1024 * 1024;                // [1024][1024]
    float* stats = (float*)WT;                           // 1 MB (over dead WqkvT)
    u16*   W1T   = WT;                                   // [4096][1024] (late)

    // 0. early weight transposes (fp32 -> bf16, B^T layout)
    transpose_w4<<<dim3(16, 16, 4), 256, 0, stream>>>(
        Wq, Wk, Wv, Wo,
        WqkvT, WqkvT + 1024u * 1024, WqkvT + 2048u * 1024, WoT);

    // 1. h = LN(x, g1, be1)
    ln_kernel<float><<<Mn, 256, 0, stream>>>(x, g1, be1, h);

    // 2. QKV = h @ [Wq|Wk|Wv]; Q pre-scaled  (ring-4 256x256 + XCD swizzle)
    gemm256<256, 0, 0, 0, 1, 0, 0, 1><<<dim3(12, 16), 512, 0, stream>>>(
        h, nullptr, En, WqkvT, En, nullptr, QKV, nullptr, nullptr, QKVLD, En);

    // 3. Vg = V^T per (b,h)
    vcopy_t<<<dim3(1, 32, 32), 256, 0, stream>>>(QKV, Vg);

    // 4. split-K flash pass 1 -> partials + stats  (1024 blocks, 4/CU)
    flash_pass1<<<dim3(32, Hn, Bn), 256, 0, stream>>>(QKV, Vg, Op0, QKV, stats);

    // 5. merge partials -> O into QKV cols [0,1024)
    flash_merge<<<Mn, 256, 0, stream>>>(QKV, Op0, stats);

    // 6. X1 = x + O @ Wo + bo  (128-family R0-structure, 12 KB LDS)
    gemm_bt<64, 1, 0, 1, 0, 0, 0, 0, 0, 1, 0><<<dim3(8, 64), 256, 0, stream>>>(
        QKV, nullptr, QKVLD, WoT, En, bo, x, X1b, nullptr, En, En);

    // 7. late weight transposes (QKV + WT + Vg regions now dead)
    transpose_w<<<dim3(64, 16), 256, 0, stream>>>(W1, W1T, 1024, 4096);
    transpose_w<<<dim3(16, 64), 256, 0, stream>>>(W2, W2T, 4096, 1024);

    // 8. h2 = LN(X1, g2, be2)
    ln_kernel<u16><<<Mn, 256, 0, stream>>>(X1b, g2, be2, h);

    // 9. FF1: relu(h2 @ W1 + b1) -> F1a/F1b  (ring-4 256x256 + XCD swizzle)
    gemm256<256, 1, 1, 1, 0, 0, 0, 1><<<dim3(16, 16), 512, 0, stream>>>(
        h, nullptr, En, W1T, En, b1, F1a, F1b, nullptr, 2048, En);

    // 9.5. init FF2 accumulator: d_out = X1 + b2 (fp32)
    ff2_init<<<Mn, 256, 0, stream>>>(X1b, b2, (float*)d_out);

    // 10. FF2: ring-4 256x128, split-K=2 atomic + XCD swizzle.
    gemm256<128, 0, 0, 0, 0, 1, 1, 1><<<dim3(8, 16, 2), 512, 0, stream>>>(
        F1a, F1b, 2048, W2T, DFFn, nullptr, nullptr, nullptr,
        (float*)d_out, En, 2048);
}

// Round 17
// 365.290 us; speedup vs baseline: 1.0989x; 1.0860x over previous
//
#include <hip/hip_runtime.h>
#include <hip/hip_bf16.h>
#include <math.h>

// Problem constants
#define Bn 2
#define Tn 2048
#define En 1024
#define Hn 16
#define DFFn 4096
#define Mn (Bn*Tn)   // 4096 rows
#define QKVLD 3072   // fused QKV leading dim

typedef __hip_bfloat16 bf16;
typedef unsigned short u16;
typedef unsigned int u32;
typedef __attribute__((ext_vector_type(8))) short short8;
typedef __attribute__((ext_vector_type(4))) float f32x4;

typedef __attribute__((address_space(1))) const void cg_void;
typedef __attribute__((address_space(3))) void lds_void;

// Q pre-scale folded into QKV GEMM: E^-0.5 * log2(e)
#define QSC 0.0450842200278f

// lgkm-only barrier: LDS writes visible + wave sync; vmcnt (global loads in
// flight to wave-private registers) NOT drained -- prefetches survive it.
#define HBAR() asm volatile("s_waitcnt lgkmcnt(0)\n\ts_barrier" ::: "memory")

__device__ __forceinline__ u16 f2bf(float f) {
    bf16 h = __float2bfloat16(f);
    u16 u; __builtin_memcpy(&u, &h, 2); return u;
}
__device__ __forceinline__ float bf2f(u16 u) {
    u32 x = ((u32)u) << 16; float f; __builtin_memcpy(&f, &x, 4); return f;
}

// ---------------- 4x weight transpose+convert (1024x1024 each) ---------------
__global__ __launch_bounds__(256)
void transpose_w4(const float* __restrict__ s0, const float* __restrict__ s1,
                  const float* __restrict__ s2, const float* __restrict__ s3,
                  u16* __restrict__ d0, u16* __restrict__ d1,
                  u16* __restrict__ d2, u16* __restrict__ d3) {
    const float* src = (blockIdx.z == 0) ? s0 : (blockIdx.z == 1) ? s1
                     : (blockIdx.z == 2) ? s2 : s3;
    u16* dst = (blockIdx.z == 0) ? d0 : (blockIdx.z == 1) ? d1
             : (blockIdx.z == 2) ? d2 : d3;
    __shared__ float t[64][65];
    const int r0 = blockIdx.y * 64, c0 = blockIdx.x * 64;
    const int tr = threadIdx.x >> 6, tc = threadIdx.x & 63;
#pragma unroll
    for (int i = 0; i < 16; i++)
        t[tr + i * 4][tc] = src[(size_t)(r0 + tr + i * 4) * 1024 + c0 + tc];
    __syncthreads();
#pragma unroll
    for (int i = 0; i < 16; i++)
        dst[(size_t)(c0 + tr + i * 4) * 1024 + r0 + tc] = f2bf(t[tc][tr + i * 4]);
}

// ---------------- generic weight transpose: src fp32 [R][C] -> bf16 [C][R] ---
__global__ __launch_bounds__(256)
void transpose_w(const float* __restrict__ src, u16* __restrict__ dst,
                 int R, int C) {
    __shared__ float t[64][65];
    const int r0 = blockIdx.y * 64, c0 = blockIdx.x * 64;
    const int tr = threadIdx.x >> 6, tc = threadIdx.x & 63;
#pragma unroll
    for (int i = 0; i < 16; i++)
        t[tr + i * 4][tc] = src[(size_t)(r0 + tr + i * 4) * C + c0 + tc];
    __syncthreads();
#pragma unroll
    for (int i = 0; i < 16; i++)
        dst[(size_t)(c0 + tr + i * 4) * R + r0 + tc] = f2bf(t[tc][tr + i * 4]);
}

// ---------------- V copy-transpose: QKV V-cols -> Vg[bh][dh=64][tok=2048] ----
__global__ __launch_bounds__(256)
void vcopy_t(const u16* __restrict__ QKV, u16* __restrict__ Vg) {
    const int bh = blockIdx.z;          // bb*16+hh
    const int t0 = blockIdx.y * 64;     // token tile
    __shared__ u16 t[64][65];
    const int tr = threadIdx.x >> 6, tc = threadIdx.x & 63;
    const u16* src = QKV + (size_t)(bh >> 4) * 2048 * QKVLD + 2048 + (bh & 15) * 64;
#pragma unroll
    for (int i = 0; i < 16; i++)
        t[tr + i * 4][tc] = src[(size_t)(t0 + tr + i * 4) * QKVLD + tc];  // [tokl][dh]
    __syncthreads();
    u16* dst = Vg + (size_t)bh * 64 * 2048;
#pragma unroll
    for (int i = 0; i < 16; i++)
        dst[(size_t)(tr + i * 4) * 2048 + t0 + tc] = t[tc][tr + i * 4];
}

// ---------------- LayerNorm: one block per row of E=1024 ---------------------
template<typename AT>
__global__ __launch_bounds__(256)
void ln_kernel(const AT* __restrict__ x, const float* __restrict__ g,
               const float* __restrict__ b, u16* __restrict__ out) {
    const int row = blockIdx.x;
    const int tid = threadIdx.x;
    const AT* xp = x + (size_t)row * En;
    float v[4];
    float s = 0.f, sq = 0.f;
#pragma unroll
    for (int i = 0; i < 4; i++) {
        if constexpr (sizeof(AT) == 2) v[i] = bf2f(xp[tid + i * 256]);
        else                           v[i] = (float)xp[tid + i * 256];
        s += v[i];
        sq += v[i] * v[i];
    }
    __shared__ float rs[256], rq[256];
    rs[tid] = s; rq[tid] = sq;
    __syncthreads();
    for (int st = 128; st > 0; st >>= 1) {
        if (tid < st) { rs[tid] += rs[tid + st]; rq[tid] += rq[tid + st]; }
        __syncthreads();
    }
    const float mu  = rs[0] * (1.0f / En);
    const float var = rq[0] * (1.0f / En) - mu * mu;
    const float inv = rsqrtf(var + 1e-5f);
#pragma unroll
    for (int i = 0; i < 4; i++) {
        const int c = tid + i * 256;
        out[(size_t)row * En + c] = f2bf((v[i] - mu) * inv * g[c] + b[c]);
    }
}

// ---------------- FF2 output init: out = X1(bf16) + b2 (fp32) ----------------
__global__ __launch_bounds__(256)
void ff2_init(const u16* __restrict__ X1, const float* __restrict__ b2,
              float* __restrict__ out) {
    const int row = blockIdx.x;
    const int c = threadIdx.x * 4;
    ushort4 a = *(const ushort4*)&X1[(size_t)row * En + c];
    float4 bb = *(const float4*)&b2[c];
    float4 o;
    o.x = bf2f(a.x) + bb.x;
    o.y = bf2f(a.y) + bb.y;
    o.z = bf2f(a.z) + bb.z;
    o.w = bf2f(a.w) + bb.w;
    *(float4*)&out[(size_t)row * En + c] = o;
}

// ---------------- 256xTN 2-phase GEMM (R14 verified best) --------------------
// C[M,N] = A(bf16 [M][K]) @ Wt(bf16 [N][K])^T. 256(M) x TN(N) tile, BK=64,
// 512 thr (8 waves). TN=256: 2Mx4N waves, per-wave 128x64, LDS 128 KB.
// TN=128: 4Mx2N waves, per-wave 64x64, LDS 96 KB. T3-minimal loop:
// {stage(next); compute(cur); vmcnt(0)+lgkmcnt(0); barrier}.
// R15/R16 refuted the ring-4/BK=32 counted-vmcnt variant: with conflicts
// fixed to 0 it still ran 82 vs 68 us (doubled barrier-pairs per K-distance
// outweigh the overlap). This 2-phase BK=64 form is the measured best.
// XSWZ: panel-per-XCD remap (FF2 FETCH 135->49 MB, R14). panel by -> XCD
// by&7 at all sites (GY=16); FF2 z-pair shares XCD; FF1-writer/FF2-reader
// panel mappings agree (R10's mismatch regression avoided).
// ATOM: split-K over gridDim.z, fp32 atomicAdd into pre-init'd outF.
// SPLITA: slice z reads A (z==0) or A2 (z==1), local cols [0,Kd).
template<int TN, int HAS_BIAS, int RELU, int SPLITC, int SCQ, int ATOM,
         int SPLITA, int XSWZ>
__global__ __launch_bounds__(512, 2)
void gemm256(const u16* __restrict__ A, const u16* __restrict__ A2, int ldA,
             const u16* __restrict__ Wt, int ldW,
             const float* __restrict__ bias,
             u16* __restrict__ Cout, u16* __restrict__ Cout2,
             float* __restrict__ outF, int ldC, int Kd) {
    constexpr int WGN = (TN == 256) ? 4 : 2;       // waves along N
    constexpr int MF  = (256 / (8 / WGN)) / 16;    // m-frags/wave: 8 or 4
    constexpr int NF  = (TN / WGN) / 16;           // n-frags/wave: 4
    __shared__ __align__(16) u16 As[2][256 * 64];
    __shared__ __align__(16) u16 Bs[2][TN * 64];
    const int tid  = threadIdx.x;
    const int lane = tid & 63, wv = tid >> 6;      // 8 waves
    const int quad = lane >> 4, l16 = lane & 15;
    const int wr = wv / WGN, wc = wv % WGN;
    const int lr8 = lane >> 3;                     // row within 8-row group
    const int gcg = (lane & 7) ^ lr8;              // swizzled source colgroup

    int bx = blockIdx.x, by = blockIdx.y, bz = blockIdx.z;
    if (XSWZ) {
        const int GX = gridDim.x, GY = gridDim.y;  // GY == 16 at all sites
        const int L = (bz * GY + by) * GX + bx;    // hw dispatch order
        const int xcd = L & 7, slot = L >> 3;
        const int p = slot / GX;                   // panel index on this XCD
        bx = slot - p * GX;                        // x sweeps consecutively
        const int yz = p * 8 + xcd;                // (y,z) panel, XCD-resident
        by = yz & (GY - 1);
        bz = yz >> 4;                              // GY=16
    }

    const int m0 = by * 256, n0 = bx * TN;
    const u16* Ap = (SPLITA && ATOM && bz) ? A2 : A;
    const int kbase = ATOM ? bz * Kd : 0;          // B-side global K offset

    f32x4 acc[MF][NF] = {};

    auto stage = [&](int buf, int kt) {            // kt = local A col
#pragma unroll
        for (int i = 0; i < 4; i++) {
            const int rbase = wv * 32 + i * 8;     // A: 32 rows/wave (256 total)
            __builtin_amdgcn_global_load_lds(
                (cg_void*)(const void*)&Ap[(size_t)(m0 + rbase + lr8) * ldA + kt + gcg * 8],
                (lds_void*)(void*)&As[buf][rbase * 64], 16, 0, 0);
        }
#pragma unroll
        for (int i = 0; i < TN / 64; i++) {        // B: TN/8 rows/wave (TN total)
            const int rbase = wv * (TN / 8) + i * 8;
            __builtin_amdgcn_global_load_lds(
                (cg_void*)(const void*)&Wt[(size_t)(n0 + rbase + lr8) * ldW + kbase + kt + gcg * 8],
                (lds_void*)(void*)&Bs[buf][rbase * 64], 16, 0, 0);
        }
    };
    auto compute = [&](int buf) {
        const int swz = l16 & 7;
#pragma unroll
        for (int ks = 0; ks < 2; ks++) {
            short8 a[MF], b[NF];
#pragma unroll
            for (int mf = 0; mf < MF; mf++)
                a[mf] = *(const short8*)&As[buf][(wr * (MF * 16) + mf * 16 + l16) * 64 +
                         (((ks * 4 + quad) ^ swz) * 8)];
#pragma unroll
            for (int nf = 0; nf < NF; nf++)
                b[nf] = *(const short8*)&Bs[buf][(wc * 64 + nf * 16 + l16) * 64 +
                         (((ks * 4 + quad) ^ swz) * 8)];
#pragma unroll
            for (int mf = 0; mf < MF; mf++)
#pragma unroll
                for (int nf = 0; nf < NF; nf++)
                    acc[mf][nf] = __builtin_amdgcn_mfma_f32_16x16x32_bf16(
                        a[mf], b[nf], acc[mf][nf], 0, 0, 0);
        }
    };

    stage(0, 0);
    asm volatile("s_waitcnt vmcnt(0)" ::: "memory");
    __builtin_amdgcn_s_barrier();
    const int NT = Kd >> 6;                        // BK=64 steps
    for (int t = 0; t < NT; ++t) {
        const int cur = t & 1;
        if (t + 1 < NT) stage(cur ^ 1, (t + 1) * 64);
        compute(cur);
        asm volatile("s_waitcnt vmcnt(0) lgkmcnt(0)" ::: "memory");
        __builtin_amdgcn_s_barrier();
    }

    const float qscale = (SCQ && n0 < 1024) ? QSC : 1.0f;
#pragma unroll
    for (int mf = 0; mf < MF; mf++) {
#pragma unroll
        for (int r = 0; r < 4; r++) {
            const int gm = m0 + wr * (MF * 16) + mf * 16 + quad * 4 + r;
#pragma unroll
            for (int nf = 0; nf < NF; nf++) {
                const int gn = n0 + wc * 64 + nf * 16 + l16;
                const int cn = SPLITC ? (gn & 2047) : gn;
                float c = acc[mf][nf][r];
                if (HAS_BIAS) c += bias[gn];
                if (RELU) c = fmaxf(c, 0.f);
                if (SCQ) c *= qscale;
                if (ATOM) {
                    atomicAdd(&outF[(size_t)gm * ldC + gn], c);
                } else {
                    u16* Cp = (SPLITC && gn >= 2048) ? Cout2 : Cout;
                    Cp[(size_t)gm * ldC + cn] = f2bf(c);
                }
            }
        }
    }
}

// ---------------- small-tile GEMM (O-proj only): R0 structure ----------------
template<int TM, int HAS_BIAS, int RELU, int RES, int OUT_F32, int SCQ,
         int SPLITC, int SPLITA, int ATOM = 0, int XSWZ = 0, int PIPE = 0>
__global__ __launch_bounds__(256)
void gemm_bt(const u16* __restrict__ A, const u16* __restrict__ A2, int ldA,
             const u16* __restrict__ Wt, int ldW,
             const float* __restrict__ bias, const void* __restrict__ res,
             void* __restrict__ Cout, void* __restrict__ Cout2,
             int ldC, int Kd) {
    constexpr int IF = TM / 32;          // i-frags per wave
    constexpr int RB = 1;
    __shared__ __align__(16) u16 As[RB][TM * 32];
    __shared__ __align__(16) u16 Bs[RB][128 * 32];
    const int tid  = threadIdx.x;
    const int lane = tid & 63, wv = tid >> 6;
    const int quad = lane >> 4, l16 = lane & 15;

    int bx = blockIdx.x, by = blockIdx.y, bz = blockIdx.z;
    if (XSWZ) {
        const int GX = gridDim.x, GY = gridDim.y;
        const int L = (bz * GY + by) * GX + bx;   // hw dispatch order
        const int xcd = L & 7, slot = L >> 3;
        const int p = slot / GX;                  // panel index on this XCD
        bx = slot - p * GX;                       // x sweeps consecutively
        const int yz = p * 8 + xcd;               // (y,z) panel, XCD-resident
        by = yz & (GY - 1);
        bz = yz >> __builtin_ctz(GY);
    }

    const int m0 = by * TM, n0 = bx * 128;
    const int rw = (wv >> 1) * (TM / 2), cw = (wv & 1) * 64;
    const int lr  = lane >> 2;                         // row within 16-row chunk
    const int gsw = ((lane & 3) ^ ((lane >> 3) & 3)) * 8;  // swizzled src colgrp
    const int psw = (quad ^ ((l16 >> 1) & 3)) * 8;     // swizzled read colgrp

    f32x4 acc[IF][4] = {};

    auto stage = [&](int buf, int kt) {
        const u16* Ap = (SPLITA && kt >= 2048) ? A2 : A;
        const int  kk = SPLITA ? (kt & 2047) : kt;
#pragma unroll
        for (int t = 0; t < TM / 64; t++) {
            const int row = wv * (TM / 4) + t * 16;
            __builtin_amdgcn_global_load_lds(
                (cg_void*)(const void*)&Ap[(size_t)(m0 + row + lr) * ldA + kk + gsw],
                (lds_void*)(void*)&As[buf][row * 32], 16, 0, 0);
        }
#pragma unroll
        for (int t = 0; t < 2; t++) {
            const int row = wv * 32 + t * 16;
            __builtin_amdgcn_global_load_lds(
                (cg_void*)(const void*)&Wt[(size_t)(n0 + row + lr) * ldW + kt + gsw],
                (lds_void*)(void*)&Bs[buf][row * 32], 16, 0, 0);
        }
    };
    auto compute = [&](int buf) {
        short8 af[IF], bfr[4];
#pragma unroll
        for (int i = 0; i < IF; i++)
            af[i] = *(const short8*)&As[buf][(rw + i * 16 + l16) * 32 + psw];
#pragma unroll
        for (int j = 0; j < 4; j++)
            bfr[j] = *(const short8*)&Bs[buf][(cw + j * 16 + l16) * 32 + psw];
#pragma unroll
        for (int i = 0; i < IF; i++)
#pragma unroll
            for (int j = 0; j < 4; j++)
                acc[i][j] = __builtin_amdgcn_mfma_f32_16x16x32_bf16(
                    af[i], bfr[j], acc[i][j], 0, 0, 0);
    };

    const int kbase = ATOM ? bz * Kd : 0;
    for (int kt = kbase; kt < kbase + Kd; kt += 32) {
        __syncthreads();
        stage(0, kt);
        __syncthreads();
        compute(0);
    }

    const float qscale = (SCQ && n0 < 1024) ? QSC : 1.0f;
    void* Cp = (SPLITC && n0 >= 2048) ? Cout2 : Cout;
#pragma unroll
    for (int i = 0; i < IF; i++) {
#pragma unroll
        for (int r = 0; r < 4; r++) {
            const int gm = m0 + rw + i * 16 + quad * 4 + r;
#pragma unroll
            for (int j = 0; j < 4; j++) {
                const int gn = n0 + cw + j * 16 + l16;
                const int cn = SPLITC ? (gn & 2047) : gn;
                float c = acc[i][j][r];
                if (HAS_BIAS) c += bias[gn];
                if (RELU) c = fmaxf(c, 0.f);
                if (RES == 1) c += ((const float*)res)[(size_t)gm * ldC + cn];
                if (RES == 2) c += bf2f(((const u16*)res)[(size_t)gm * ldC + cn]);
                if (SCQ) c *= qscale;
                if (ATOM) {
                    atomicAdd(&((float*)Cp)[(size_t)gm * ldC + cn], c);
                } else if (OUT_F32) {
                    ((float*)Cp)[(size_t)gm * ldC + cn] = c;
                } else {
                    ((u16*)Cp)[(size_t)gm * ldC + cn] = f2bf(c);
                }
            }
        }
    }
}

// ---------------- Flash attention pass 1 (split-K) ---------------------------
__global__ __launch_bounds__(256)
void flash_pass1(const u16* __restrict__ QKV, const u16* __restrict__ Vg,
                 u16* __restrict__ Op0, u16* __restrict__ Op1qkv,
                 float* __restrict__ stats) {
    const int pr = blockIdx.x >> 1, half = blockIdx.x & 1;
    const int hh = blockIdx.y, bb = blockIdx.z;
    const int tid  = threadIdx.x;
    const int lane = tid & 63, wv = tid >> 6;
    const int quad = lane >> 4, l16 = lane & 15;

    __shared__ __align__(16) u16 Ks[2][64 * 64];
    __shared__ __align__(16) u16 Vt[2][64 * 64];
    __shared__ __align__(16) u16 Ps[4][16 * 64];

    const size_t rowbase = (size_t)(bb * Tn) * QKVLD;
    const u16* Vgh = Vg + (size_t)(bb * Hn + hh) * 64 * 2048;

    const int sr = tid >> 2;
    const int p0 = (tid & 3) | ((sr & 1) << 2);
    const int p1 = p0 ^ 4;
    const int g0 = p0 ^ (sr & 7), g1 = p1 ^ (sr & 7);
    const int lsw = l16 & 7;                       // fragment-read row swizzle

    uint4 kA, kB, vA, vB;
    auto prefetch = [&](int kt) {
        const size_t kb = rowbase + (size_t)(kt * 64 + sr) * QKVLD + 1024 + hh * 64;
        kA = *(const uint4*)&QKV[kb + g0 * 8];
        kB = *(const uint4*)&QKV[kb + g1 * 8];
        const size_t vb = (size_t)sr * 2048 + kt * 64;
        vA = *(const uint4*)&Vgh[vb + g0 * 8];
        vB = *(const uint4*)&Vgh[vb + g1 * 8];
    };
    auto writebuf = [&](int buf) {
        *(uint4*)&Ks[buf][sr * 64 + p0 * 8] = kA;
        *(uint4*)&Ks[buf][sr * 64 + p1 * 8] = kB;
        *(uint4*)&Vt[buf][sr * 64 + p0 * 8] = vA;
        *(uint4*)&Vt[buf][sr * 64 + p1 * 8] = vB;
    };

    for (int qsel = 0; qsel < 2; qsel++) {
        const int qt = qsel ? (31 - pr) : pr;
        const int nk = (qt >= half) ? ((qt - half) >> 1) + 1 : 0;
        const int qrow = qt * 64 + wv * 16 + l16;
        const int grow = bb * Tn + qrow;

        f32x4 ot[4] = {};
        float m2 = -INFINITY, lrow = 0.f;

        HBAR();
        if (nk > 0) {
            const u16* qp = QKV + rowbase + (size_t)qrow * QKVLD + hh * 64;
            short8 qf[2];
            qf[0] = *(const short8*)&qp[quad * 8];
            qf[1] = *(const short8*)&qp[32 + quad * 8];

            prefetch(half);
            writebuf(0);
            if (nk > 1) prefetch(half + 2);
            HBAR();

            const bool hasdiag = ((qt ^ half) & 1) == 0;
            for (int f = 0; f < nk; f++) {
                const int cur = f & 1;

                f32x4 st[4] = {};
#pragma unroll
                for (int ks = 0; ks < 2; ks++)
#pragma unroll
                    for (int i = 0; i < 4; i++) {
                        short8 kf = *(const short8*)&Ks[cur][(i * 16 + l16) * 64 +
                                     (((ks * 4 + quad) ^ lsw) * 8)];
                        st[i] = __builtin_amdgcn_mfma_f32_16x16x32_bf16(
                            kf, qf[ks], st[i], 0, 0, 0);
                    }

                float tmax = -INFINITY;
                if (hasdiag && f == nk - 1) {
                    const int qloc = wv * 16 + l16;
#pragma unroll
                    for (int i = 0; i < 4; i++)
#pragma unroll
                        for (int r = 0; r < 4; r++) {
                            float s = st[i][r];
                            if (i * 16 + quad * 4 + r > qloc) s = -INFINITY;
                            st[i][r] = s;
                            tmax = fmaxf(tmax, s);
                        }
                } else {
#pragma unroll
                    for (int i = 0; i < 4; i++)
#pragma unroll
                        for (int r = 0; r < 4; r++)
                            tmax = fmaxf(tmax, st[i][r]);
                }
                tmax = fmaxf(tmax, __shfl_xor(tmax, 16));
                tmax = fmaxf(tmax, __shfl_xor(tmax, 32));

                const float mnew = fmaxf(m2, tmax);
                const float alpha = exp2f(m2 - mnew);
                m2 = mnew;
                float psum = 0.f;
#pragma unroll
                for (int i = 0; i < 4; i++)
#pragma unroll
                    for (int r = 0; r < 4; r++) {
                        const float e = exp2f(st[i][r] - mnew);
                        st[i][r] = e;
                        psum += e;
                    }
                psum += __shfl_xor(psum, 16);
                psum += __shfl_xor(psum, 32);
                lrow = lrow * alpha + psum;
#pragma unroll
                for (int i = 0; i < 4; i++) ot[i] *= alpha;

#pragma unroll
                for (int i = 0; i < 4; i++) {
                    uint2 w;
                    w.x = (u32)f2bf(st[i][0]) | ((u32)f2bf(st[i][1]) << 16);
                    w.y = (u32)f2bf(st[i][2]) | ((u32)f2bf(st[i][3]) << 16);
                    const int g = (i * 2 + (quad >> 1)) ^ lsw;
                    *(uint2*)&Ps[wv][l16 * 64 + g * 8 + (quad & 1) * 4] = w;
                }
                asm volatile("s_waitcnt lgkmcnt(0)" ::: "memory");

#pragma unroll
                for (int ks = 0; ks < 2; ks++) {
                    short8 pf = *(const short8*)&Ps[wv][l16 * 64 +
                                 (((ks * 4 + quad) ^ lsw) * 8)];
#pragma unroll
                    for (int i = 0; i < 4; i++) {
                        short8 vf = *(const short8*)&Vt[cur][(i * 16 + l16) * 64 +
                                     (((ks * 4 + quad) ^ lsw) * 8)];
                        ot[i] = __builtin_amdgcn_mfma_f32_16x16x32_bf16(
                            vf, pf, ot[i], 0, 0, 0);
                    }
                }

                if (f + 1 < nk) {
                    writebuf(cur ^ 1);
                    if (f + 2 < nk) prefetch(half + 2 * (f + 2));
                    HBAR();
                }
            }
        }

        u16* op = (half == 0) ? (Op0 + (size_t)grow * 1024 + hh * 64)
                              : (Op1qkv + (size_t)grow * QKVLD + 2048 + hh * 64);
#pragma unroll
        for (int i = 0; i < 4; i++) {
            ushort4 o4;
            o4.x = f2bf(ot[i][0]); o4.y = f2bf(ot[i][1]);
            o4.z = f2bf(ot[i][2]); o4.w = f2bf(ot[i][3]);
            *(ushort4*)&op[i * 16 + quad * 4] = o4;
        }
        if (quad == 0) {
            stats[((size_t)(half * 2 + 0) * 4096 + grow) * 16 + hh] = m2;
            stats[((size_t)(half * 2 + 1) * 4096 + grow) * 16 + hh] = lrow;
        }
    }
}

// ---------------- Flash merge: O = (w0 Oa + w1 Ob) / (w0 l0 + w1 l1) ---------
__global__ __launch_bounds__(256)
void flash_merge(u16* __restrict__ QKV, const u16* __restrict__ Op0,
                 const float* __restrict__ stats) {
    const int row = blockIdx.x;
    const int tid = threadIdx.x;
    const int col = tid * 4;
    const int hh = col >> 6;
    const float m0 = stats[((size_t)0 * 4096 + row) * 16 + hh];
    const float l0 = stats[((size_t)1 * 4096 + row) * 16 + hh];
    const float m1 = stats[((size_t)2 * 4096 + row) * 16 + hh];
    const float l1 = stats[((size_t)3 * 4096 + row) * 16 + hh];
    const float m  = fmaxf(m0, m1);
    const float w0 = exp2f(m0 - m), w1 = exp2f(m1 - m);
    const float inv = 1.0f / (w0 * l0 + w1 * l1);
    ushort4 a = *(const ushort4*)&Op0[(size_t)row * 1024 + col];
    ushort4 b = *(const ushort4*)&QKV[(size_t)row * QKVLD + 2048 + col];
    ushort4 o;
    o.x = f2bf((w0 * bf2f(a.x) + w1 * bf2f(b.x)) * inv);
    o.y = f2bf((w0 * bf2f(a.y) + w1 * bf2f(b.y)) * inv);
    o.z = f2bf((w0 * bf2f(a.z) + w1 * bf2f(b.z)) * inv);
    o.w = f2bf((w0 * bf2f(a.w) + w1 * bf2f(b.w)) * inv);
    *(ushort4*)&QKV[(size_t)row * QKVLD + col] = o;
}

// ---------------- Launcher ---------------------------------------------------
// Inputs fp32, output fp32 [B,T,E].
extern "C" void kernel_launch(void* const* d_in, const int* in_sizes, int n_in,
                              void* d_out, int out_size, void* d_ws, size_t ws_size,
                              hipStream_t stream) {
    const float* x   = (const float*)d_in[0];
    const float* Wq  = (const float*)d_in[1];
    const float* Wk  = (const float*)d_in[2];
    const float* Wv  = (const float*)d_in[3];
    const float* Wo  = (const float*)d_in[4];
    const float* bo  = (const float*)d_in[5];
    const float* W1  = (const float*)d_in[6];
    const float* b1  = (const float*)d_in[7];
    const float* W2  = (const float*)d_in[8];
    const float* b2  = (const float*)d_in[9];
    const float* g1  = (const float*)d_in[10];
    const float* be1 = (const float*)d_in[11];
    const float* g2  = (const float*)d_in[12];
    const float* be2 = (const float*)d_in[13];

    // Workspace (40 MB):
    //   [ 0,24M): QKV bf16 [4096][3072]; after O-proj: F1a [0,16M) [4096][2048]
    //   [16,24M): W2T bf16 [1024][4096] (written after O-proj)
    //   [24,32M): Op0 bf16 [4096][1024]; later X1 bf16 (same slot)
    //   [32,40M): Vg [32][64][2048] (V^T per (b,h)); after flash: F1b [4096][2048]
    // d_out (16 MB fp32): [0,8M) h bf16; [8,16M): WqkvT(6M)+WoT(2M) early;
    //   stats (1M over dead WqkvT) during flash; W1T (8M) late.
    //   After FF1: whole d_out becomes the fp32 FF2 accumulator (init + atomics).
    char* wsb = (char*)d_ws;
    u16*   QKV = (u16*)wsb;
    u16*   F1a = (u16*)wsb;                              // [4096][2048]
    u16*   W2T = (u16*)(wsb + 16u * 1024 * 1024);        // [1024][4096]
    u16*   Op0 = (u16*)(wsb + 24u * 1024 * 1024);        // [4096][1024]
    u16*   X1b = Op0;                                    // X1 bf16, same slot
    u16*   Vg  = (u16*)(wsb + 32u * 1024 * 1024);        // [32][64][2048]
    u16*   F1b = Vg;                                     // [4096][2048]
    u16*   h     = (u16*)d_out;
    u16*   WT    = (u16*)((char*)d_out + 8u * 1024 * 1024);
    u16*   WqkvT = WT;                                   // [3072][1024] (early)
    u16*   WoT   = WT + 3u * 1024 * 1024;                // [1024][1024]
    float* stats = (float*)WT;                           // 1 MB (over dead WqkvT)
    u16*   W1T   = WT;                                   // [4096][1024] (late)

    // 0. early weight transposes (fp32 -> bf16, B^T layout)
    transpose_w4<<<dim3(16, 16, 4), 256, 0, stream>>>(
        Wq, Wk, Wv, Wo,
        WqkvT, WqkvT + 1024u * 1024, WqkvT + 2048u * 1024, WoT);

    // 1. h = LN(x, g1, be1)
    ln_kernel<float><<<Mn, 256, 0, stream>>>(x, g1, be1, h);

    // 2. QKV = h @ [Wq|Wk|Wv]; Q pre-scaled  (256x256 2-phase + XCD swizzle)
    gemm256<256, 0, 0, 0, 1, 0, 0, 1><<<dim3(12, 16), 512, 0, stream>>>(
        h, nullptr, En, WqkvT, En, nullptr, QKV, nullptr, nullptr, QKVLD, En);

    // 3. Vg = V^T per (b,h)
    vcopy_t<<<dim3(1, 32, 32), 256, 0, stream>>>(QKV, Vg);

    // 4. split-K flash pass 1 -> partials + stats  (1024 blocks, 4/CU)
    flash_pass1<<<dim3(32, Hn, Bn), 256, 0, stream>>>(QKV, Vg, Op0, QKV, stats);

    // 5. merge partials -> O into QKV cols [0,1024)
    flash_merge<<<Mn, 256, 0, stream>>>(QKV, Op0, stats);

    // 6. X1 = x + O @ Wo + bo  (128-family R0-structure, 12 KB LDS)
    gemm_bt<64, 1, 0, 1, 0, 0, 0, 0, 0, 1, 0><<<dim3(8, 64), 256, 0, stream>>>(
        QKV, nullptr, QKVLD, WoT, En, bo, x, X1b, nullptr, En, En);

    // 7. late weight transposes (QKV + WT + Vg regions now dead)
    transpose_w<<<dim3(64, 16), 256, 0, stream>>>(W1, W1T, 1024, 4096);
    transpose_w<<<dim3(16, 64), 256, 0, stream>>>(W2, W2T, 4096, 1024);

    // 8. h2 = LN(X1, g2, be2)
    ln_kernel<u16><<<Mn, 256, 0, stream>>>(X1b, g2, be2, h);

    // 9. FF1: relu(h2 @ W1 + b1) -> F1a/F1b  (256x256 2-phase + XCD swizzle)
    gemm256<256, 1, 1, 1, 0, 0, 0, 1><<<dim3(16, 16), 512, 0, stream>>>(
        h, nullptr, En, W1T, En, b1, F1a, F1b, nullptr, 2048, En);

    // 9.5. init FF2 accumulator: d_out = X1 + b2 (fp32)
    ff2_init<<<Mn, 256, 0, stream>>>(X1b, b2, (float*)d_out);

    // 10. FF2: 256x128-tile 2-phase, split-K=2 atomic + XCD swizzle.
    gemm256<128, 0, 0, 0, 0, 1, 1, 1><<<dim3(8, 16, 2), 512, 0, stream>>>(
        F1a, F1b, 2048, W2T, DFFn, nullptr, nullptr, nullptr,
        (float*)d_out, En, 2048);
}